// Round 3
// baseline (342.610 us; speedup 1.0000x reference)
//
#include <hip/hip_runtime.h>

namespace {

constexpr int LEN   = 160;
constexpr int PLANE = LEN * LEN;            // 25600
constexpr int VOL   = LEN * PLANE;          // 4,096,000 per batch
constexpr float INV_SZ = 1.0f / 125.0f;
constexpr float EPS_   = 1e-10f;

constexpr int TX = 32, TY = 32, ZC = 8;     // 1000 blocks (~3.9/CU available)
constexpr int RX = TX + 4, RY = TY + 4;     // 36
constexpr int NRAW = RX * RY;               // 1296
constexpr int NCHZ = LEN / ZC;              // 20
constexpr int NBX = LEN / TX, NBY = LEN / TY; // 5 x 5
constexpr int NXY = NBX * NBY;              // 25 tiles per z-slab
constexpr int BLK  = 512;
constexpr int NXT  = RY * (TX / 4);         // 288 x-sum tasks per field

__device__ __forceinline__ int clampi(int v) {
  return v < 0 ? 0 : (v > LEN - 1 ? LEN - 1 : v);
}

// Swizzle: put all 25 xy-tiles of one z-slab on one XCD (HW round-robins
// linear block id across 8 XCDs). 1000 = 8 classes x 125, each class =
// 5 slabs x 25 tiles -> bijective. Perf-only; correctness never depends on it.
// Measured effect (R2): FETCH_SIZE 112 MB -> 48.5 MB per slab2 dispatch.
struct BlkInfo { int x0, y0, z0; size_t base; };
__device__ __forceinline__ BlkInfo decodeBlock() {
  const int g = blockIdx.x + NBX * (blockIdx.y + NBY * blockIdx.z);
  const int c = g & 7, k = g >> 3;
  const int s = c + 8 * (k / NXY);          // slab id 0..39 (zchunk x batch)
  const int w = k % NXY;                    // tile within slab
  BlkInfo bi;
  bi.x0 = (w % NBX) * TX;
  bi.y0 = (w / NBX) * TY;
  bi.z0 = (s % NCHZ) * ZC;
  bi.base = (size_t)(s / NCHZ) * VOL;
  return bi;
}

// ---------------------------------------------------------------------------
// Two-field slab box3, software-pipelined, 2 barriers/plane, 1-deep prefetch.
// __launch_bounds__(512,8): 8 waves/SIMD -> VGPR<=64 -> 4 blocks/CU resident
// (R2 lesson: 2-deep prefetch cost 68 VGPR -> 16-wave cap -> 2 blocks/CU).
// All LDS traffic vectorized (b128 x-sum tasks, b64 y-sums/cen).
// MODE 0: outA = inA - box3(inA)/125 ; outB likewise.
// MODE 1: raw LDS holds unsquared values; x-sum squares on read.
//         outA = (inA/(sqrt(box3(inA^2)/125)+eps)) * (inB/(sqrt(box3(inB^2)/125)+eps))
// ---------------------------------------------------------------------------
template <int MODE>
__global__ __launch_bounds__(BLK, 8) void slab2(const float* __restrict__ inA,
                                                const float* __restrict__ inB,
                                                float* __restrict__ outA,
                                                float* __restrict__ outB) {
  __shared__ __align__(16) float raw[2][RY][RX];   // 10.4 KB
  __shared__ __align__(16) float xs[2][RY][RX];    // 10.4 KB (cols 32..35 pad)

  const int tid = threadIdx.x;
  const BlkInfo bi = decodeBlock();
  const int x0 = bi.x0, y0 = bi.y0, z0 = bi.z0;
  const size_t base = bi.base;

  // plane-invariant halo-load descriptors (3 predicated rounds)
  int off[3], lly[3], llx[3];
  bool act[3];
#pragma unroll
  for (int j = 0; j < 3; ++j) {
    int i = tid + j * BLK;
    act[j] = i < NRAW;
    int ii = act[j] ? i : 0;
    lly[j] = ii / RX; llx[j] = ii % RX;
    off[j] = clampi(y0 - 2 + lly[j]) * LEN + clampi(x0 - 2 + llx[j]);
  }

  // owned output pixels: 2 consecutive in x
  const int ly  = tid >> 4;           // 0..31
  const int lx0 = (tid & 15) * 2;     // 0,2,..,30

  float pfA[3], pfB[3];
  float2 rzA[5], rzB[5];              // z-ring of xy-sums
  float2 cenA[3], cenB[3];            // center-value ring, lag 2

  auto loadPlane = [&](int zp) {
    const size_t pb = base + (size_t)clampi(zp) * PLANE;
#pragma unroll
    for (int j = 0; j < 3; ++j)
      if (act[j]) { pfA[j] = inA[pb + off[j]]; pfB[j] = inB[pb + off[j]]; }
  };
  auto depositLDS = [&]() {
#pragma unroll
    for (int j = 0; j < 3; ++j)
      if (act[j]) { raw[0][lly[j]][llx[j]] = pfA[j]; raw[1][lly[j]][llx[j]] = pfB[j]; }
  };

  // 4-wide sliding x-sum task: t in [0, 2*NXT)
  auto xsumTask = [&](int t) {
    const int f = t & 1, c = (t >> 1) & 7, r = t >> 4;
    const float* rp = &raw[f][r][4 * c];
    float4 u = *(const float4*)rp;
    float4 v = *(const float4*)(rp + 4);
    if (MODE == 1) {
      u.x *= u.x; u.y *= u.y; u.z *= u.z; u.w *= u.w;
      v.x *= v.x; v.y *= v.y; v.z *= v.z; v.w *= v.w;
    }
    const float m = u.y + u.z + u.w;
    float4 s;
    s.x = m + u.x + v.x;          // a0..a4
    s.y = m + v.x + v.y;          // a1..a5
    s.z = s.y - u.y + v.z;        // a2..a6
    s.w = s.z - u.z + v.w;        // a3..a7
    *(float4*)&xs[f][r][4 * c] = s;
  };

  loadPlane(z0 - 2);
  depositLDS();
  __syncthreads();

  for (int zp = z0 - 2; zp <= z0 + ZC + 1; ++zp) {
    if (zp <= z0 + ZC) loadPlane(zp + 1);   // prefetch in flight during compute

    xsumTask(tid);
    if (tid < 2 * NXT - BLK) xsumTask(tid + BLK);   // 64 extra tasks

    // center stash (unsquared), ring shift: cen[0] ends up at lag 2
    cenA[0] = cenA[1]; cenA[1] = cenA[2];
    cenB[0] = cenB[1]; cenB[1] = cenB[2];
    cenA[2] = *(const float2*)&raw[0][ly + 2][lx0 + 2];
    cenB[2] = *(const float2*)&raw[1][ly + 2][lx0 + 2];

    __syncthreads();                        // xs ready; all raw reads done

    if (zp <= z0 + ZC) depositLDS();        // raw <- plane zp+1 (waits on prefetch)

    // y-sums into register z-ring
#pragma unroll
    for (int s = 0; s < 4; ++s) { rzA[s] = rzA[s + 1]; rzB[s] = rzB[s + 1]; }
    {
      float2 sa = {0.f, 0.f}, sb = {0.f, 0.f};
#pragma unroll
      for (int k = 0; k < 5; ++k) {
        const float2 a = *(const float2*)&xs[0][ly + k][lx0];
        const float2 b = *(const float2*)&xs[1][ly + k][lx0];
        sa.x += a.x; sa.y += a.y; sb.x += b.x; sb.y += b.y;
      }
      rzA[4] = sa; rzB[4] = sb;
    }

    if (zp >= z0 + 2) {
      const int zo = zp - 2;
      float2 bsA = {0.f, 0.f}, bsB = {0.f, 0.f};
#pragma unroll
      for (int s = 0; s < 5; ++s) {
        bsA.x += rzA[s].x; bsA.y += rzA[s].y;
        bsB.x += rzB[s].x; bsB.y += rzB[s].y;
      }
      const size_t g = base + (size_t)zo * PLANE + (size_t)(y0 + ly) * LEN + (x0 + lx0);
      if (MODE == 0) {
        float2 oa, ob;
        oa.x = cenA[0].x - bsA.x * INV_SZ; oa.y = cenA[0].y - bsA.y * INV_SZ;
        ob.x = cenB[0].x - bsB.x * INV_SZ; ob.y = cenB[0].y - bsB.y * INV_SZ;
        *(float2*)&outA[g] = oa;
        *(float2*)&outB[g] = ob;
      } else {
        float2 o;
        o.x = (cenA[0].x / (sqrtf(bsA.x * INV_SZ) + EPS_)) *
              (cenB[0].x / (sqrtf(bsB.x * INV_SZ) + EPS_));
        o.y = (cenA[0].y / (sqrtf(bsA.y * INV_SZ) + EPS_)) *
              (cenB[0].y / (sqrtf(bsB.y * INV_SZ) + EPS_));
        *(float2*)&outA[g] = o;
      }
    }
    __syncthreads();                        // raw(zp+1) ready; xs reads done
  }
}

// ---------------------------------------------------------------------------
// Stage C: cross = box3(p); acc += cross^2 * mask; block reduce -> atomicAdd.
// Same vectorized LDS scheme, single field, 1-deep prefetch.
// ---------------------------------------------------------------------------
__global__ __launch_bounds__(BLK, 8) void slab1_reduce(const float* __restrict__ p,
                                                       const float* __restrict__ mask,
                                                       float* __restrict__ out) {
  __shared__ __align__(16) float raw[RY][RX];
  __shared__ __align__(16) float xs[RY][RX];
  __shared__ float wsum[BLK / 64];

  const int tid = threadIdx.x;
  const BlkInfo bi = decodeBlock();
  const int x0 = bi.x0, y0 = bi.y0, z0 = bi.z0;
  const size_t base = bi.base;

  int off[3], lly[3], llx[3];
  bool act[3];
#pragma unroll
  for (int j = 0; j < 3; ++j) {
    int i = tid + j * BLK;
    act[j] = i < NRAW;
    int ii = act[j] ? i : 0;
    lly[j] = ii / RX; llx[j] = ii % RX;
    off[j] = clampi(y0 - 2 + lly[j]) * LEN + clampi(x0 - 2 + llx[j]);
  }
  const int ly  = tid >> 4;
  const int lx0 = (tid & 15) * 2;

  float pf[3];
  float2 rz[5];
  float acc = 0.f;

  auto loadPlane = [&](int zp) {
    const size_t pb = base + (size_t)clampi(zp) * PLANE;
#pragma unroll
    for (int j = 0; j < 3; ++j)
      if (act[j]) pf[j] = p[pb + off[j]];
  };
  auto depositLDS = [&]() {
#pragma unroll
    for (int j = 0; j < 3; ++j)
      if (act[j]) raw[lly[j]][llx[j]] = pf[j];
  };

  loadPlane(z0 - 2);
  depositLDS();
  __syncthreads();

  for (int zp = z0 - 2; zp <= z0 + ZC + 1; ++zp) {
    if (zp <= z0 + ZC) loadPlane(zp + 1);

    if (tid < NXT) {                        // 288 x-sum tasks
      const int c = tid & 7, r = tid >> 3;
      const float* rp = &raw[r][4 * c];
      const float4 u = *(const float4*)rp;
      const float4 v = *(const float4*)(rp + 4);
      const float m = u.y + u.z + u.w;
      float4 s;
      s.x = m + u.x + v.x;
      s.y = m + v.x + v.y;
      s.z = s.y - u.y + v.z;
      s.w = s.z - u.z + v.w;
      *(float4*)&xs[r][4 * c] = s;
    }
    __syncthreads();

    if (zp <= z0 + ZC) depositLDS();

#pragma unroll
    for (int s = 0; s < 4; ++s) rz[s] = rz[s + 1];
    {
      float2 s2 = {0.f, 0.f};
#pragma unroll
      for (int k = 0; k < 5; ++k) {
        const float2 a = *(const float2*)&xs[ly + k][lx0];
        s2.x += a.x; s2.y += a.y;
      }
      rz[4] = s2;
    }

    if (zp >= z0 + 2) {
      const int zo = zp - 2;
      float2 bs = {0.f, 0.f};
#pragma unroll
      for (int s = 0; s < 5; ++s) { bs.x += rz[s].x; bs.y += rz[s].y; }
      const size_t g = base + (size_t)zo * PLANE + (size_t)(y0 + ly) * LEN + (x0 + lx0);
      const float2 mk = *(const float2*)&mask[g];
      acc += bs.x * bs.x * mk.x + bs.y * bs.y * mk.y;
    }
    __syncthreads();
  }

#pragma unroll
  for (int o = 32; o > 0; o >>= 1) acc += __shfl_down(acc, o, 64);
  const int lane = tid & 63, wid = tid >> 6;
  if (lane == 0) wsum[wid] = acc;
  __syncthreads();
  if (tid == 0) {
    float t = 0.f;
#pragma unroll
    for (int w = 0; w < BLK / 64; ++w) t += wsum[w];
    atomicAdd(out, -t);
  }
}

}  // namespace

extern "C" void kernel_launch(void* const* d_in, const int* in_sizes, int n_in,
                              void* d_out, int out_size, void* d_ws, size_t ws_size,
                              hipStream_t stream) {
  const float* F    = (const float*)d_in[0];
  const float* M    = (const float*)d_in[1];
  const float* mask = (const float*)d_in[2];
  float* out = (float*)d_out;

  const size_t bufB = (size_t)(2 * VOL) * sizeof(float);
  char* ws = (char*)d_ws;
  float* dF = (float*)ws;
  float* dM = (float*)(ws + bufB);
  float* pB = (float*)(ws + 2 * bufB);

  hipMemsetAsync(d_out, 0, sizeof(float), stream);

  dim3 grd(NBX, NBY, NCHZ * 2), blk(BLK);

  slab2<0><<<grd, blk, 0, stream>>>(F, M, dF, dM);
  slab2<1><<<grd, blk, 0, stream>>>(dF, dM, pB, nullptr);
  slab1_reduce<<<grd, blk, 0, stream>>>(pB, mask, out);
}

// Round 4
// 214.770 us; speedup vs baseline: 1.5952x; 1.5952x over previous
//
#include <hip/hip_runtime.h>

namespace {

constexpr int LEN   = 160;
constexpr int PLANE = LEN * LEN;            // 25600
constexpr int VOL   = LEN * PLANE;          // 4,096,000 per batch
constexpr float INV_SZ = 1.0f / 125.0f;
constexpr float EPS_   = 1e-10f;

constexpr int TX = 32, TY = 32, ZC = 8;     // 1000 blocks (~4/CU available)
constexpr int RX = TX + 4, RY = TY + 4;     // 36
constexpr int NRAW = RX * RY;               // 1296
constexpr int NCHZ = LEN / ZC;              // 20
constexpr int NBX = LEN / TX, NBY = LEN / TY; // 5 x 5
constexpr int NXY = NBX * NBY;              // 25 tiles per z-slab
constexpr int BLK  = 512;
constexpr int NXT  = RY * (TX / 4);         // 288 x-sum tasks per field

__device__ __forceinline__ int clampi(int v) {
  return v < 0 ? 0 : (v > LEN - 1 ? LEN - 1 : v);
}

// Swizzle: put all 25 xy-tiles of one z-slab on one XCD (HW round-robins
// linear block id across 8 XCDs). 1000 = 8 classes x 125, each class =
// 5 slabs x 25 tiles -> bijective. Perf-only; correctness never depends on it.
// Measured effect (R2): FETCH_SIZE 112 MB -> 48.5 MB per slab2 dispatch.
struct BlkInfo { int x0, y0, z0; size_t base; };
__device__ __forceinline__ BlkInfo decodeBlock() {
  const int g = blockIdx.x + NBX * (blockIdx.y + NBY * blockIdx.z);
  const int c = g & 7, k = g >> 3;
  const int s = c + 8 * (k / NXY);          // slab id 0..39 (zchunk x batch)
  const int w = k % NXY;                    // tile within slab
  BlkInfo bi;
  bi.x0 = (w % NBX) * TX;
  bi.y0 = (w / NBX) * TY;
  bi.z0 = (s % NCHZ) * ZC;
  bi.base = (size_t)(s / NCHZ) * VOL;
  return bi;
}

// ---------------------------------------------------------------------------
// Two-field slab box3, software-pipelined, 2 barriers/plane, 1-deep prefetch.
// NO min-waves launch bound: R3 showed __launch_bounds__(512,8) forces
// VGPR=32 + scratch spills (WRITE_SIZE 64->187 MB, 2x slower). Natural
// allocation is ~36-44 VGPR <= 64 -> 32 waves/CU -> 4 blocks/CU resident
// (thread cap 2048/512 = 4; LDS 21KB allows 7).
// All LDS traffic vectorized (b128 x-sum tasks, b64 y-sums/cen).
// MODE 0: outA = inA - box3(inA)/125 ; outB likewise.
// MODE 1: raw LDS holds unsquared values; x-sum squares on read.
//         outA = (inA/(sqrt(box3(inA^2)/125)+eps)) * (inB/(sqrt(box3(inB^2)/125)+eps))
// ---------------------------------------------------------------------------
template <int MODE>
__global__ __launch_bounds__(BLK) void slab2(const float* __restrict__ inA,
                                             const float* __restrict__ inB,
                                             float* __restrict__ outA,
                                             float* __restrict__ outB) {
  __shared__ __align__(16) float raw[2][RY][RX];   // 10.4 KB
  __shared__ __align__(16) float xs[2][RY][RX];    // 10.4 KB (cols 32..35 pad)

  const int tid = threadIdx.x;
  const BlkInfo bi = decodeBlock();
  const int x0 = bi.x0, y0 = bi.y0, z0 = bi.z0;
  const size_t base = bi.base;

  // plane-invariant halo-load descriptors (3 predicated rounds)
  int off[3], lly[3], llx[3];
  bool act[3];
#pragma unroll
  for (int j = 0; j < 3; ++j) {
    int i = tid + j * BLK;
    act[j] = i < NRAW;
    int ii = act[j] ? i : 0;
    lly[j] = ii / RX; llx[j] = ii % RX;
    off[j] = clampi(y0 - 2 + lly[j]) * LEN + clampi(x0 - 2 + llx[j]);
  }

  // owned output pixels: 2 consecutive in x
  const int ly  = tid >> 4;           // 0..31
  const int lx0 = (tid & 15) * 2;     // 0,2,..,30

  float pfA[3], pfB[3];
  float2 rzA[5], rzB[5];              // z-ring of xy-sums
  float2 cenA[3], cenB[3];            // center-value ring, lag 2

  auto loadPlane = [&](int zp) {
    const size_t pb = base + (size_t)clampi(zp) * PLANE;
#pragma unroll
    for (int j = 0; j < 3; ++j)
      if (act[j]) { pfA[j] = inA[pb + off[j]]; pfB[j] = inB[pb + off[j]]; }
  };
  auto depositLDS = [&]() {
#pragma unroll
    for (int j = 0; j < 3; ++j)
      if (act[j]) { raw[0][lly[j]][llx[j]] = pfA[j]; raw[1][lly[j]][llx[j]] = pfB[j]; }
  };

  // 4-wide sliding x-sum task: t in [0, 2*NXT)
  auto xsumTask = [&](int t) {
    const int f = t & 1, c = (t >> 1) & 7, r = t >> 4;
    const float* rp = &raw[f][r][4 * c];
    float4 u = *(const float4*)rp;
    float4 v = *(const float4*)(rp + 4);
    if (MODE == 1) {
      u.x *= u.x; u.y *= u.y; u.z *= u.z; u.w *= u.w;
      v.x *= v.x; v.y *= v.y; v.z *= v.z; v.w *= v.w;
    }
    const float m = u.y + u.z + u.w;
    float4 s;
    s.x = m + u.x + v.x;          // a0..a4
    s.y = m + v.x + v.y;          // a1..a5
    s.z = s.y - u.y + v.z;        // a2..a6
    s.w = s.z - u.z + v.w;        // a3..a7
    *(float4*)&xs[f][r][4 * c] = s;
  };

  loadPlane(z0 - 2);
  depositLDS();
  __syncthreads();

  for (int zp = z0 - 2; zp <= z0 + ZC + 1; ++zp) {
    if (zp <= z0 + ZC) loadPlane(zp + 1);   // prefetch in flight during compute

    xsumTask(tid);
    if (tid < 2 * NXT - BLK) xsumTask(tid + BLK);   // 64 extra tasks

    // center stash (unsquared), ring shift: cen[0] ends up at lag 2
    cenA[0] = cenA[1]; cenA[1] = cenA[2];
    cenB[0] = cenB[1]; cenB[1] = cenB[2];
    cenA[2] = *(const float2*)&raw[0][ly + 2][lx0 + 2];
    cenB[2] = *(const float2*)&raw[1][ly + 2][lx0 + 2];

    __syncthreads();                        // xs ready; all raw reads done

    if (zp <= z0 + ZC) depositLDS();        // raw <- plane zp+1 (waits on prefetch)

    // y-sums into register z-ring
#pragma unroll
    for (int s = 0; s < 4; ++s) { rzA[s] = rzA[s + 1]; rzB[s] = rzB[s + 1]; }
    {
      float2 sa = {0.f, 0.f}, sb = {0.f, 0.f};
#pragma unroll
      for (int k = 0; k < 5; ++k) {
        const float2 a = *(const float2*)&xs[0][ly + k][lx0];
        const float2 b = *(const float2*)&xs[1][ly + k][lx0];
        sa.x += a.x; sa.y += a.y; sb.x += b.x; sb.y += b.y;
      }
      rzA[4] = sa; rzB[4] = sb;
    }

    if (zp >= z0 + 2) {
      const int zo = zp - 2;
      float2 bsA = {0.f, 0.f}, bsB = {0.f, 0.f};
#pragma unroll
      for (int s = 0; s < 5; ++s) {
        bsA.x += rzA[s].x; bsA.y += rzA[s].y;
        bsB.x += rzB[s].x; bsB.y += rzB[s].y;
      }
      const size_t g = base + (size_t)zo * PLANE + (size_t)(y0 + ly) * LEN + (x0 + lx0);
      if (MODE == 0) {
        float2 oa, ob;
        oa.x = cenA[0].x - bsA.x * INV_SZ; oa.y = cenA[0].y - bsA.y * INV_SZ;
        ob.x = cenB[0].x - bsB.x * INV_SZ; ob.y = cenB[0].y - bsB.y * INV_SZ;
        *(float2*)&outA[g] = oa;
        *(float2*)&outB[g] = ob;
      } else {
        float2 o;
        o.x = (cenA[0].x / (sqrtf(bsA.x * INV_SZ) + EPS_)) *
              (cenB[0].x / (sqrtf(bsB.x * INV_SZ) + EPS_));
        o.y = (cenA[0].y / (sqrtf(bsA.y * INV_SZ) + EPS_)) *
              (cenB[0].y / (sqrtf(bsB.y * INV_SZ) + EPS_));
        *(float2*)&outA[g] = o;
      }
    }
    __syncthreads();                        // raw(zp+1) ready; xs reads done
  }
}

// ---------------------------------------------------------------------------
// Stage C: cross = box3(p); acc += cross^2 * mask; block reduce -> atomicAdd.
// Same vectorized LDS scheme, single field, 1-deep prefetch.
// ---------------------------------------------------------------------------
__global__ __launch_bounds__(BLK) void slab1_reduce(const float* __restrict__ p,
                                                    const float* __restrict__ mask,
                                                    float* __restrict__ out) {
  __shared__ __align__(16) float raw[RY][RX];
  __shared__ __align__(16) float xs[RY][RX];
  __shared__ float wsum[BLK / 64];

  const int tid = threadIdx.x;
  const BlkInfo bi = decodeBlock();
  const int x0 = bi.x0, y0 = bi.y0, z0 = bi.z0;
  const size_t base = bi.base;

  int off[3], lly[3], llx[3];
  bool act[3];
#pragma unroll
  for (int j = 0; j < 3; ++j) {
    int i = tid + j * BLK;
    act[j] = i < NRAW;
    int ii = act[j] ? i : 0;
    lly[j] = ii / RX; llx[j] = ii % RX;
    off[j] = clampi(y0 - 2 + lly[j]) * LEN + clampi(x0 - 2 + llx[j]);
  }
  const int ly  = tid >> 4;
  const int lx0 = (tid & 15) * 2;

  float pf[3];
  float2 rz[5];
  float acc = 0.f;

  auto loadPlane = [&](int zp) {
    const size_t pb = base + (size_t)clampi(zp) * PLANE;
#pragma unroll
    for (int j = 0; j < 3; ++j)
      if (act[j]) pf[j] = p[pb + off[j]];
  };
  auto depositLDS = [&]() {
#pragma unroll
    for (int j = 0; j < 3; ++j)
      if (act[j]) raw[lly[j]][llx[j]] = pf[j];
  };

  loadPlane(z0 - 2);
  depositLDS();
  __syncthreads();

  for (int zp = z0 - 2; zp <= z0 + ZC + 1; ++zp) {
    if (zp <= z0 + ZC) loadPlane(zp + 1);

    if (tid < NXT) {                        // 288 x-sum tasks
      const int c = tid & 7, r = tid >> 3;
      const float* rp = &raw[r][4 * c];
      const float4 u = *(const float4*)rp;
      const float4 v = *(const float4*)(rp + 4);
      const float m = u.y + u.z + u.w;
      float4 s;
      s.x = m + u.x + v.x;
      s.y = m + v.x + v.y;
      s.z = s.y - u.y + v.z;
      s.w = s.z - u.z + v.w;
      *(float4*)&xs[r][4 * c] = s;
    }
    __syncthreads();

    if (zp <= z0 + ZC) depositLDS();

#pragma unroll
    for (int s = 0; s < 4; ++s) rz[s] = rz[s + 1];
    {
      float2 s2 = {0.f, 0.f};
#pragma unroll
      for (int k = 0; k < 5; ++k) {
        const float2 a = *(const float2*)&xs[ly + k][lx0];
        s2.x += a.x; s2.y += a.y;
      }
      rz[4] = s2;
    }

    if (zp >= z0 + 2) {
      const int zo = zp - 2;
      float2 bs = {0.f, 0.f};
#pragma unroll
      for (int s = 0; s < 5; ++s) { bs.x += rz[s].x; bs.y += rz[s].y; }
      const size_t g = base + (size_t)zo * PLANE + (size_t)(y0 + ly) * LEN + (x0 + lx0);
      const float2 mk = *(const float2*)&mask[g];
      acc += bs.x * bs.x * mk.x + bs.y * bs.y * mk.y;
    }
    __syncthreads();
  }

#pragma unroll
  for (int o = 32; o > 0; o >>= 1) acc += __shfl_down(acc, o, 64);
  const int lane = tid & 63, wid = tid >> 6;
  if (lane == 0) wsum[wid] = acc;
  __syncthreads();
  if (tid == 0) {
    float t = 0.f;
#pragma unroll
    for (int w = 0; w < BLK / 64; ++w) t += wsum[w];
    atomicAdd(out, -t);
  }
}

}  // namespace

extern "C" void kernel_launch(void* const* d_in, const int* in_sizes, int n_in,
                              void* d_out, int out_size, void* d_ws, size_t ws_size,
                              hipStream_t stream) {
  const float* F    = (const float*)d_in[0];
  const float* M    = (const float*)d_in[1];
  const float* mask = (const float*)d_in[2];
  float* out = (float*)d_out;

  const size_t bufB = (size_t)(2 * VOL) * sizeof(float);
  char* ws = (char*)d_ws;
  float* dF = (float*)ws;
  float* dM = (float*)(ws + bufB);
  float* pB = (float*)(ws + 2 * bufB);

  hipMemsetAsync(d_out, 0, sizeof(float), stream);

  dim3 grd(NBX, NBY, NCHZ * 2), blk(BLK);

  slab2<0><<<grd, blk, 0, stream>>>(F, M, dF, dM);
  slab2<1><<<grd, blk, 0, stream>>>(dF, dM, pB, nullptr);
  slab1_reduce<<<grd, blk, 0, stream>>>(pB, mask, out);
}

// Round 5
// 213.173 us; speedup vs baseline: 1.6072x; 1.0075x over previous
//
#include <hip/hip_runtime.h>

namespace {

constexpr int LEN   = 160;
constexpr int PLANE = LEN * LEN;            // 25600
constexpr int VOL   = LEN * PLANE;          // 4,096,000 per batch
constexpr float INV_SZ = 1.0f / 125.0f;
constexpr float EPS_   = 1e-10f;

constexpr int TX = 32, TY = 32, ZC = 8;     // 1000 blocks
constexpr int RX = TX + 4, RY = TY + 4;     // 36
constexpr int RXS = 40;                     // slab1 xs row stride (16B-aligned rows)
constexpr int NRAW = RX * RY;               // 1296
constexpr int NCHZ = LEN / ZC;              // 20
constexpr int NBX = LEN / TX, NBY = LEN / TY; // 5 x 5
constexpr int NXY = NBX * NBY;              // 25 tiles per z-slab
constexpr int BLK  = 512;
constexpr int NXT  = RY * (TX / 4);         // 288 x-sum tasks per field

__device__ __forceinline__ int clampi(int v) {
  return v < 0 ? 0 : (v > LEN - 1 ? LEN - 1 : v);
}

// Swizzle: all 25 xy-tiles of one z-slab on one XCD (HW round-robins linear
// block id across 8 XCDs). 1000 = 8 x 125, bijective. Perf-only.
// Measured (R2): FETCH_SIZE 112 MB -> 48.5 MB per slab2 dispatch.
struct BlkInfo { int x0, y0, z0; size_t base; };
__device__ __forceinline__ BlkInfo decodeBlock() {
  const int g = blockIdx.x + NBX * (blockIdx.y + NBY * blockIdx.z);
  const int c = g & 7, k = g >> 3;
  const int s = c + 8 * (k / NXY);          // slab id 0..39 (zchunk x batch)
  const int w = k % NXY;                    // tile within slab
  BlkInfo bi;
  bi.x0 = (w % NBX) * TX;
  bi.y0 = (w / NBX) * TY;
  bi.z0 = (s % NCHZ) * ZC;
  bi.base = (size_t)(s / NCHZ) * VOL;
  return bi;
}

// ---------------------------------------------------------------------------
// Two-field slab box3. R5: LDS-pipe is the binder (wall invariant to
// residency/grid across R1/R2/R4) -> cut LDS wave-instructions.
// y-sum ownership 2x2 quads (256 threads, both fields): xs rows shared
// between adjacent output rows -> 6 b64/field/quad (24 wave-instr/plane,
// was 80). cen/stores also quad-based.
// MODE 0: outA = inA - box3(inA)/125 ; outB likewise.
// MODE 1: raw holds unsquared; x-sum squares on read.
//         outA = (inA/(sqrt(box3(inA^2)/125)+eps)) * (inB/(sqrt(box3(inB^2)/125)+eps))
// ---------------------------------------------------------------------------
template <int MODE>
__global__ __launch_bounds__(BLK) void slab2(const float* __restrict__ inA,
                                             const float* __restrict__ inB,
                                             float* __restrict__ outA,
                                             float* __restrict__ outB) {
  __shared__ __align__(16) float raw[2][RY][RX];   // 10.4 KB
  __shared__ __align__(16) float xs[2][RY][RX];    // 10.4 KB

  const int tid = threadIdx.x;
  const BlkInfo bi = decodeBlock();
  const int x0 = bi.x0, y0 = bi.y0, z0 = bi.z0;
  const size_t base = bi.base;

  // plane-invariant halo-load descriptors (3 predicated rounds)
  int off[3], lly[3], llx[3];
  bool act[3];
#pragma unroll
  for (int j = 0; j < 3; ++j) {
    int i = tid + j * BLK;
    act[j] = i < NRAW;
    int ii = act[j] ? i : 0;
    lly[j] = ii / RX; llx[j] = ii % RX;
    off[j] = clampi(y0 - 2 + lly[j]) * LEN + clampi(x0 - 2 + llx[j]);
  }

  // quad ownership: threads 0..255 own a 2(y) x 2(x) output quad, both fields
  const bool qact = tid < 256;
  const int qy  = (tid & 255) >> 4;   // 0..15
  const int ry0 = 2 * qy, ry1 = 2 * qy + 1;
  const int cx  = (tid & 15) * 2;     // 0,2,..,30

  float pfA[3], pfB[3];
  float2 rzA[5][2], rzB[5][2];        // z-ring of xy-sums, per quad row
  float2 cenA[3][2], cenB[3][2];      // center ring, lag 2, per quad row

  auto loadPlane = [&](int zp) {
    const size_t pb = base + (size_t)clampi(zp) * PLANE;
#pragma unroll
    for (int j = 0; j < 3; ++j)
      if (act[j]) { pfA[j] = inA[pb + off[j]]; pfB[j] = inB[pb + off[j]]; }
  };
  auto depositLDS = [&]() {
#pragma unroll
    for (int j = 0; j < 3; ++j)
      if (act[j]) { raw[0][lly[j]][llx[j]] = pfA[j]; raw[1][lly[j]][llx[j]] = pfB[j]; }
  };

  // 4-wide sliding x-sum task: t in [0, 2*NXT)
  auto xsumTask = [&](int t) {
    const int f = t & 1, c = (t >> 1) & 7, r = t >> 4;
    const float* rp = &raw[f][r][4 * c];
    float4 u = *(const float4*)rp;
    float4 v = *(const float4*)(rp + 4);
    if (MODE == 1) {
      u.x *= u.x; u.y *= u.y; u.z *= u.z; u.w *= u.w;
      v.x *= v.x; v.y *= v.y; v.z *= v.z; v.w *= v.w;
    }
    const float m = u.y + u.z + u.w;
    float4 s;
    s.x = m + u.x + v.x;          // a0..a4
    s.y = m + v.x + v.y;          // a1..a5
    s.z = s.y - u.y + v.z;        // a2..a6
    s.w = s.z - u.z + v.w;        // a3..a7
    *(float4*)&xs[f][r][4 * c] = s;
  };

  loadPlane(z0 - 2);
  depositLDS();
  __syncthreads();

  for (int zp = z0 - 2; zp <= z0 + ZC + 1; ++zp) {
    if (zp <= z0 + ZC) loadPlane(zp + 1);   // prefetch in flight during compute

    xsumTask(tid);
    if (tid < 2 * NXT - BLK) xsumTask(tid + BLK);   // 64 extra tasks

    if (qact) {
      // center stash (unsquared), ring shift: [0] ends up at lag 2
#pragma unroll
      for (int s = 0; s < 2; ++s)
#pragma unroll
        for (int r = 0; r < 2; ++r) {
          cenA[s][r] = cenA[s + 1][r]; cenB[s][r] = cenB[s + 1][r];
        }
      cenA[2][0] = *(const float2*)&raw[0][ry0 + 2][cx + 2];
      cenA[2][1] = *(const float2*)&raw[0][ry1 + 2][cx + 2];
      cenB[2][0] = *(const float2*)&raw[1][ry0 + 2][cx + 2];
      cenB[2][1] = *(const float2*)&raw[1][ry1 + 2][cx + 2];
    }

    __syncthreads();                        // xs ready; all raw reads done

    if (zp <= z0 + ZC) depositLDS();        // raw <- plane zp+1 (waits on prefetch)

    if (qact) {
      // y-sums into register z-ring: 6 shared xs rows serve both quad rows
#pragma unroll
      for (int s = 0; s < 4; ++s)
#pragma unroll
        for (int r = 0; r < 2; ++r) {
          rzA[s][r] = rzA[s + 1][r]; rzB[s][r] = rzB[s + 1][r];
        }
      float2 sA0 = {0.f, 0.f}, sA1 = {0.f, 0.f};
      float2 sB0 = {0.f, 0.f}, sB1 = {0.f, 0.f};
#pragma unroll
      for (int k = 0; k < 6; ++k) {
        const float2 a = *(const float2*)&xs[0][ry0 + k][cx];
        const float2 b = *(const float2*)&xs[1][ry0 + k][cx];
        if (k < 5) { sA0.x += a.x; sA0.y += a.y; sB0.x += b.x; sB0.y += b.y; }
        if (k > 0) { sA1.x += a.x; sA1.y += a.y; sB1.x += b.x; sB1.y += b.y; }
      }
      rzA[4][0] = sA0; rzA[4][1] = sA1;
      rzB[4][0] = sB0; rzB[4][1] = sB1;

      if (zp >= z0 + 2) {
        const int zo = zp - 2;
#pragma unroll
        for (int r = 0; r < 2; ++r) {
          float2 bsA = {0.f, 0.f}, bsB = {0.f, 0.f};
#pragma unroll
          for (int s = 0; s < 5; ++s) {
            bsA.x += rzA[s][r].x; bsA.y += rzA[s][r].y;
            bsB.x += rzB[s][r].x; bsB.y += rzB[s][r].y;
          }
          const int ry = 2 * qy + r;
          const size_t g = base + (size_t)zo * PLANE + (size_t)(y0 + ry) * LEN + (x0 + cx);
          if (MODE == 0) {
            float2 oa, ob;
            oa.x = cenA[0][r].x - bsA.x * INV_SZ; oa.y = cenA[0][r].y - bsA.y * INV_SZ;
            ob.x = cenB[0][r].x - bsB.x * INV_SZ; ob.y = cenB[0][r].y - bsB.y * INV_SZ;
            *(float2*)&outA[g] = oa;
            *(float2*)&outB[g] = ob;
          } else {
            float2 o;
            o.x = (cenA[0][r].x / (sqrtf(bsA.x * INV_SZ) + EPS_)) *
                  (cenB[0][r].x / (sqrtf(bsB.x * INV_SZ) + EPS_));
            o.y = (cenA[0][r].y / (sqrtf(bsA.y * INV_SZ) + EPS_)) *
                  (cenB[0][r].y / (sqrtf(bsB.y * INV_SZ) + EPS_));
            *(float2*)&outA[g] = o;
          }
        }
      }
    }
    __syncthreads();                        // raw(zp+1) ready; xs reads done
  }
}

// ---------------------------------------------------------------------------
// Stage C: cross = box3(p); acc += cross^2 * mask; block reduce -> atomicAdd.
// 2x4 quads (128 threads) with b128 y-sum reads; xs rows padded to RXS=40
// floats so every row is 16B-aligned. mask loaded as float4.
// ---------------------------------------------------------------------------
__global__ __launch_bounds__(BLK) void slab1_reduce(const float* __restrict__ p,
                                                    const float* __restrict__ mask,
                                                    float* __restrict__ out) {
  __shared__ __align__(16) float raw[RY][RX];
  __shared__ __align__(16) float xs[RY][RXS];
  __shared__ float wsum[BLK / 64];

  const int tid = threadIdx.x;
  const BlkInfo bi = decodeBlock();
  const int x0 = bi.x0, y0 = bi.y0, z0 = bi.z0;
  const size_t base = bi.base;

  int off[3], lly[3], llx[3];
  bool act[3];
#pragma unroll
  for (int j = 0; j < 3; ++j) {
    int i = tid + j * BLK;
    act[j] = i < NRAW;
    int ii = act[j] ? i : 0;
    lly[j] = ii / RX; llx[j] = ii % RX;
    off[j] = clampi(y0 - 2 + lly[j]) * LEN + clampi(x0 - 2 + llx[j]);
  }

  // 2x4 quad ownership: threads 0..127 own 2 rows x 4 cols
  const bool qact = tid < 128;
  const int qy  = (tid & 127) >> 3;   // 0..15
  const int ry0 = 2 * qy;
  const int cx  = (tid & 7) * 4;      // 0,4,..,28

  float pf[3];
  float4 rz[5][2];
  float acc = 0.f;

  auto loadPlane = [&](int zp) {
    const size_t pb = base + (size_t)clampi(zp) * PLANE;
#pragma unroll
    for (int j = 0; j < 3; ++j)
      if (act[j]) pf[j] = p[pb + off[j]];
  };
  auto depositLDS = [&]() {
#pragma unroll
    for (int j = 0; j < 3; ++j)
      if (act[j]) raw[lly[j]][llx[j]] = pf[j];
  };

  loadPlane(z0 - 2);
  depositLDS();
  __syncthreads();

  for (int zp = z0 - 2; zp <= z0 + ZC + 1; ++zp) {
    if (zp <= z0 + ZC) loadPlane(zp + 1);

    if (tid < NXT) {                        // 288 x-sum tasks
      const int c = tid & 7, r = tid >> 3;
      const float* rp = &raw[r][4 * c];
      const float4 u = *(const float4*)rp;
      const float4 v = *(const float4*)(rp + 4);
      const float m = u.y + u.z + u.w;
      float4 s;
      s.x = m + u.x + v.x;
      s.y = m + v.x + v.y;
      s.z = s.y - u.y + v.z;
      s.w = s.z - u.z + v.w;
      *(float4*)&xs[r][4 * c] = s;
    }
    __syncthreads();

    if (zp <= z0 + ZC) depositLDS();

    if (qact) {
#pragma unroll
      for (int s = 0; s < 4; ++s)
#pragma unroll
        for (int r = 0; r < 2; ++r) rz[s][r] = rz[s + 1][r];
      float4 s0 = {0.f, 0.f, 0.f, 0.f}, s1 = {0.f, 0.f, 0.f, 0.f};
#pragma unroll
      for (int k = 0; k < 6; ++k) {
        const float4 a = *(const float4*)&xs[ry0 + k][cx];
        if (k < 5) { s0.x += a.x; s0.y += a.y; s0.z += a.z; s0.w += a.w; }
        if (k > 0) { s1.x += a.x; s1.y += a.y; s1.z += a.z; s1.w += a.w; }
      }
      rz[4][0] = s0; rz[4][1] = s1;

      if (zp >= z0 + 2) {
        const int zo = zp - 2;
#pragma unroll
        for (int r = 0; r < 2; ++r) {
          float4 bs = {0.f, 0.f, 0.f, 0.f};
#pragma unroll
          for (int s = 0; s < 5; ++s) {
            bs.x += rz[s][r].x; bs.y += rz[s][r].y;
            bs.z += rz[s][r].z; bs.w += rz[s][r].w;
          }
          const int ry = 2 * qy + r;
          const size_t g = base + (size_t)zo * PLANE + (size_t)(y0 + ry) * LEN + (x0 + cx);
          const float4 mk = *(const float4*)&mask[g];
          acc += bs.x * bs.x * mk.x + bs.y * bs.y * mk.y +
                 bs.z * bs.z * mk.z + bs.w * bs.w * mk.w;
        }
      }
    }
    __syncthreads();
  }

#pragma unroll
  for (int o = 32; o > 0; o >>= 1) acc += __shfl_down(acc, o, 64);
  const int lane = tid & 63, wid = tid >> 6;
  if (lane == 0) wsum[wid] = acc;
  __syncthreads();
  if (tid == 0) {
    float t = 0.f;
#pragma unroll
    for (int w = 0; w < BLK / 64; ++w) t += wsum[w];
    atomicAdd(out, -t);
  }
}

}  // namespace

extern "C" void kernel_launch(void* const* d_in, const int* in_sizes, int n_in,
                              void* d_out, int out_size, void* d_ws, size_t ws_size,
                              hipStream_t stream) {
  const float* F    = (const float*)d_in[0];
  const float* M    = (const float*)d_in[1];
  const float* mask = (const float*)d_in[2];
  float* out = (float*)d_out;

  const size_t bufB = (size_t)(2 * VOL) * sizeof(float);
  char* ws = (char*)d_ws;
  float* dF = (float*)ws;
  float* dM = (float*)(ws + bufB);
  float* pB = (float*)(ws + 2 * bufB);

  hipMemsetAsync(d_out, 0, sizeof(float), stream);

  dim3 grd(NBX, NBY, NCHZ * 2), blk(BLK);

  slab2<0><<<grd, blk, 0, stream>>>(F, M, dF, dM);
  slab2<1><<<grd, blk, 0, stream>>>(dF, dM, pB, nullptr);
  slab1_reduce<<<grd, blk, 0, stream>>>(pB, mask, out);
}

// Round 6
// 187.424 us; speedup vs baseline: 1.8280x; 1.1374x over previous
//
#include <hip/hip_runtime.h>

namespace {

constexpr int LEN   = 160;
constexpr int PLANE = LEN * LEN;            // 25600
constexpr int VOL   = LEN * PLANE;          // 4,096,000 per batch
constexpr float INV_SZ = 1.0f / 125.0f;
constexpr float EPS_   = 1e-10f;

constexpr int TX = 32, TY = 32, ZC = 16;    // 500 blocks, z-amp 1.25
constexpr int RX = TX + 4, RY = TY + 4;     // 36
constexpr int NRAW = RX * RY;               // 1296
constexpr int NCHZ = LEN / ZC;              // 10
constexpr int NBX = LEN / TX, NBY = LEN / TY; // 5 x 5
constexpr int NXY = NBX * NBY;              // 25 tiles per z-slab
constexpr int BLK  = 512;
constexpr int NWG  = NBX * NBY * NCHZ * 2;  // 500
constexpr int QW   = NWG / 8, RW = NWG % 8; // 62, 4 (m204 bijective swizzle)

__device__ __forceinline__ int clampi(int v) {
  return v < 0 ? 0 : (v > LEN - 1 ? LEN - 1 : v);
}

// Bijective XCD swizzle for NWG=500 (not %8==0): class xcd = g%8 gets a
// contiguous chunk of work ids (m204). Keeps all 25 xy-tiles of a z-slab
// (mostly) on one XCD. Perf-only. Measured (R2): FETCH 112->48.5 MB.
struct BlkInfo { int x0, y0, z0; size_t base; };
__device__ __forceinline__ BlkInfo decodeBlock() {
  const int g = blockIdx.x + NBX * (blockIdx.y + NBY * blockIdx.z);
  const int xcd = g & 7, idx = g >> 3;
  const int w = (xcd < RW) ? xcd * (QW + 1) + idx
                           : RW * (QW + 1) + (xcd - RW) * QW + idx;
  const int half = NWG / 2;                 // 250 work items per batch
  const int batch = w / half;
  const int rem   = w % half;
  const int zc = rem / NXY, tl = rem % NXY;
  BlkInfo bi;
  bi.x0 = (tl % NBX) * TX;
  bi.y0 = (tl / NBX) * TY;
  bi.z0 = zc * ZC;
  bi.base = (size_t)batch * VOL;
  return bi;
}

// ---------------------------------------------------------------------------
// Two-field slab box3, PLANE-PAIR pipelined (R6): each iteration stages and
// processes TWO z-planes -> 1 barrier per plane (was 2), half the exposed
// global-load waits, 2x independent work between barriers. Rings shift by 2.
// R1/R2/R4/R5 showed wall is a serial per-plane latency chain, invariant to
// residency/LDS-instr-count -> amortize the chain over 2 planes.
// MODE 0: outA = inA - box3(inA)/125 ; outB likewise.
// MODE 1: raw holds unsquared; x-sum squares on read.
//         outA = (inA/(sqrt(box3(inA^2)/125)+eps)) * (inB/(sqrt(box3(inB^2)/125)+eps))
// ---------------------------------------------------------------------------
template <int MODE>
__global__ __launch_bounds__(BLK) void slab2(const float* __restrict__ inA,
                                             const float* __restrict__ inB,
                                             float* __restrict__ outA,
                                             float* __restrict__ outB) {
  __shared__ __align__(16) float raw[2][2][RY][RX];   // [field][plane] 20.7KB
  __shared__ __align__(16) float xs [2][2][RY][RX];   // 20.7KB

  const int tid = threadIdx.x;
  const BlkInfo bi = decodeBlock();
  const int x0 = bi.x0, y0 = bi.y0, z0 = bi.z0;
  const size_t base = bi.base;

  // plane-invariant halo-load descriptors (3 predicated rounds)
  int off[3], lly[3], llx[3];
  bool act[3];
#pragma unroll
  for (int j = 0; j < 3; ++j) {
    int i = tid + j * BLK;
    act[j] = i < NRAW;
    int ii = act[j] ? i : 0;
    lly[j] = ii / RX; llx[j] = ii % RX;
    off[j] = clampi(y0 - 2 + lly[j]) * LEN + clampi(x0 - 2 + llx[j]);
  }

  // owned output pixels: one float2 per plane per field
  const int ly  = tid >> 4;           // 0..31
  const int lx0 = (tid & 15) * 2;     // 0,2,..,30

  float pA[2][3], pB[2][3];           // prefetch pair regs
  float2 rzA[6], rzB[6];              // z-ring of xy-sums (6 live entries)
  float2 cnA[4], cnB[4];              // center ring (lag 2, pair-push)

  auto loadPair = [&](int t) {
#pragma unroll
    for (int p = 0; p < 2; ++p) {
      const size_t pb = base + (size_t)clampi(t + p) * PLANE;
#pragma unroll
      for (int j = 0; j < 3; ++j)
        if (act[j]) { pA[p][j] = inA[pb + off[j]]; pB[p][j] = inB[pb + off[j]]; }
    }
  };
  auto depositPair = [&]() {
#pragma unroll
    for (int p = 0; p < 2; ++p)
#pragma unroll
      for (int j = 0; j < 3; ++j)
        if (act[j]) {
          raw[0][p][lly[j]][llx[j]] = pA[p][j];
          raw[1][p][lly[j]][llx[j]] = pB[p][j];
        }
  };

  // 4-wide sliding x-sum task, both planes: tt in [0, 576)
  auto xsumTask = [&](int tt) {
    const int f = tt & 1, c = (tt >> 1) & 7, r = tt >> 4;
#pragma unroll
    for (int p = 0; p < 2; ++p) {
      const float* rp = &raw[f][p][r][4 * c];
      float4 u = *(const float4*)rp;
      float4 v = *(const float4*)(rp + 4);
      if (MODE == 1) {
        u.x *= u.x; u.y *= u.y; u.z *= u.z; u.w *= u.w;
        v.x *= v.x; v.y *= v.y; v.z *= v.z; v.w *= v.w;
      }
      const float m = u.y + u.z + u.w;
      float4 s;
      s.x = m + u.x + v.x;          // a0..a4
      s.y = m + v.x + v.y;          // a1..a5
      s.z = s.y - u.y + v.z;        // a2..a6
      s.w = s.z - u.z + v.w;        // a3..a7
      *(float4*)&xs[f][p][r][4 * c] = s;
    }
  };

  loadPair(z0 - 2);
  depositPair();
  __syncthreads();

  for (int t = z0 - 2; t <= z0 + ZC; t += 2) {
    if (t + 2 <= z0 + ZC) loadPair(t + 2);   // prefetch next pair

    xsumTask(tid);
    if (tid < 576 - BLK) xsumTask(tid + BLK);   // 64 extra tasks

    // center ring: shift 2, push cen(t), cen(t+1); cn[0]=cen(t-2), cn[1]=cen(t-1)
    cnA[0] = cnA[2]; cnA[1] = cnA[3]; cnB[0] = cnB[2]; cnB[1] = cnB[3];
    cnA[2] = *(const float2*)&raw[0][0][ly + 2][lx0 + 2];
    cnA[3] = *(const float2*)&raw[0][1][ly + 2][lx0 + 2];
    cnB[2] = *(const float2*)&raw[1][0][ly + 2][lx0 + 2];
    cnB[3] = *(const float2*)&raw[1][1][ly + 2][lx0 + 2];

    __syncthreads();                        // xs ready; all raw reads done

    if (t + 2 <= z0 + ZC) depositPair();    // raw <- pair (t+2,t+3)

    // z-ring: shift 2, push yd(t), yd(t+1); rz[k] = yd(t-4+k)
#pragma unroll
    for (int s = 0; s < 4; ++s) { rzA[s] = rzA[s + 2]; rzB[s] = rzB[s + 2]; }
#pragma unroll
    for (int p = 0; p < 2; ++p) {
      float2 sa = {0.f, 0.f}, sb = {0.f, 0.f};
#pragma unroll
      for (int k = 0; k < 5; ++k) {
        const float2 a = *(const float2*)&xs[0][p][ly + k][lx0];
        const float2 b = *(const float2*)&xs[1][p][ly + k][lx0];
        sa.x += a.x; sa.y += a.y; sb.x += b.x; sb.y += b.y;
      }
      rzA[4 + p] = sa; rzB[4 + p] = sb;
    }

    // emit planes zp = t-2, t-1
    if (t >= z0 + 2) {
#pragma unroll
      for (int q = 0; q < 2; ++q) {
        const int zo = t - 2 + q;
        float2 bsA = {0.f, 0.f}, bsB = {0.f, 0.f};
#pragma unroll
        for (int s = 0; s < 5; ++s) {
          bsA.x += rzA[q + s].x; bsA.y += rzA[q + s].y;
          bsB.x += rzB[q + s].x; bsB.y += rzB[q + s].y;
        }
        const size_t g = base + (size_t)zo * PLANE + (size_t)(y0 + ly) * LEN + (x0 + lx0);
        if (MODE == 0) {
          float2 oa, ob;
          oa.x = cnA[q].x - bsA.x * INV_SZ; oa.y = cnA[q].y - bsA.y * INV_SZ;
          ob.x = cnB[q].x - bsB.x * INV_SZ; ob.y = cnB[q].y - bsB.y * INV_SZ;
          *(float2*)&outA[g] = oa;
          *(float2*)&outB[g] = ob;
        } else {
          float2 o;
          o.x = (cnA[q].x / (sqrtf(bsA.x * INV_SZ) + EPS_)) *
                (cnB[q].x / (sqrtf(bsB.x * INV_SZ) + EPS_));
          o.y = (cnA[q].y / (sqrtf(bsA.y * INV_SZ) + EPS_)) *
                (cnB[q].y / (sqrtf(bsB.y * INV_SZ) + EPS_));
          *(float2*)&outA[g] = o;
        }
      }
    }
    __syncthreads();                        // raw pair ready; xs reads done
  }
}

// ---------------------------------------------------------------------------
// Stage C: cross = box3(p); acc += cross^2 * mask; block reduce -> atomicAdd.
// Same plane-pair pipeline, single field.
// ---------------------------------------------------------------------------
__global__ __launch_bounds__(BLK) void slab1_reduce(const float* __restrict__ p,
                                                    const float* __restrict__ mask,
                                                    float* __restrict__ out) {
  __shared__ __align__(16) float raw[2][RY][RX];   // [plane] 10.4KB
  __shared__ __align__(16) float xs [2][RY][RX];   // 10.4KB
  __shared__ float wsum[BLK / 64];

  const int tid = threadIdx.x;
  const BlkInfo bi = decodeBlock();
  const int x0 = bi.x0, y0 = bi.y0, z0 = bi.z0;
  const size_t base = bi.base;

  int off[3], lly[3], llx[3];
  bool act[3];
#pragma unroll
  for (int j = 0; j < 3; ++j) {
    int i = tid + j * BLK;
    act[j] = i < NRAW;
    int ii = act[j] ? i : 0;
    lly[j] = ii / RX; llx[j] = ii % RX;
    off[j] = clampi(y0 - 2 + lly[j]) * LEN + clampi(x0 - 2 + llx[j]);
  }
  const int ly  = tid >> 4;
  const int lx0 = (tid & 15) * 2;

  float pf[2][3];
  float2 rz[6];
  float acc = 0.f;

  auto loadPair = [&](int t) {
#pragma unroll
    for (int pp = 0; pp < 2; ++pp) {
      const size_t pb = base + (size_t)clampi(t + pp) * PLANE;
#pragma unroll
      for (int j = 0; j < 3; ++j)
        if (act[j]) pf[pp][j] = p[pb + off[j]];
    }
  };
  auto depositPair = [&]() {
#pragma unroll
    for (int pp = 0; pp < 2; ++pp)
#pragma unroll
      for (int j = 0; j < 3; ++j)
        if (act[j]) raw[pp][lly[j]][llx[j]] = pf[pp][j];
  };

  loadPair(z0 - 2);
  depositPair();
  __syncthreads();

  for (int t = z0 - 2; t <= z0 + ZC; t += 2) {
    if (t + 2 <= z0 + ZC) loadPair(t + 2);

    if (tid < 288) {                        // x-sum tasks, both planes
      const int c = tid & 7, r = tid >> 3;
#pragma unroll
      for (int pp = 0; pp < 2; ++pp) {
        const float* rp = &raw[pp][r][4 * c];
        const float4 u = *(const float4*)rp;
        const float4 v = *(const float4*)(rp + 4);
        const float m = u.y + u.z + u.w;
        float4 s;
        s.x = m + u.x + v.x;
        s.y = m + v.x + v.y;
        s.z = s.y - u.y + v.z;
        s.w = s.z - u.z + v.w;
        *(float4*)&xs[pp][r][4 * c] = s;
      }
    }
    __syncthreads();

    if (t + 2 <= z0 + ZC) depositPair();

#pragma unroll
    for (int s = 0; s < 4; ++s) rz[s] = rz[s + 2];
#pragma unroll
    for (int pp = 0; pp < 2; ++pp) {
      float2 s2 = {0.f, 0.f};
#pragma unroll
      for (int k = 0; k < 5; ++k) {
        const float2 a = *(const float2*)&xs[pp][ly + k][lx0];
        s2.x += a.x; s2.y += a.y;
      }
      rz[4 + pp] = s2;
    }

    if (t >= z0 + 2) {
#pragma unroll
      for (int q = 0; q < 2; ++q) {
        const int zo = t - 2 + q;
        float2 bs = {0.f, 0.f};
#pragma unroll
        for (int s = 0; s < 5; ++s) { bs.x += rz[q + s].x; bs.y += rz[q + s].y; }
        const size_t g = base + (size_t)zo * PLANE + (size_t)(y0 + ly) * LEN + (x0 + lx0);
        const float2 mk = *(const float2*)&mask[g];
        acc += bs.x * bs.x * mk.x + bs.y * bs.y * mk.y;
      }
    }
    __syncthreads();
  }

#pragma unroll
  for (int o = 32; o > 0; o >>= 1) acc += __shfl_down(acc, o, 64);
  const int lane = tid & 63, wid = tid >> 6;
  if (lane == 0) wsum[wid] = acc;
  __syncthreads();
  if (tid == 0) {
    float t = 0.f;
#pragma unroll
    for (int w = 0; w < BLK / 64; ++w) t += wsum[w];
    atomicAdd(out, -t);
  }
}

}  // namespace

extern "C" void kernel_launch(void* const* d_in, const int* in_sizes, int n_in,
                              void* d_out, int out_size, void* d_ws, size_t ws_size,
                              hipStream_t stream) {
  const float* F    = (const float*)d_in[0];
  const float* M    = (const float*)d_in[1];
  const float* mask = (const float*)d_in[2];
  float* out = (float*)d_out;

  const size_t bufB = (size_t)(2 * VOL) * sizeof(float);
  char* ws = (char*)d_ws;
  float* dF = (float*)ws;
  float* dM = (float*)(ws + bufB);
  float* pB = (float*)(ws + 2 * bufB);

  hipMemsetAsync(d_out, 0, sizeof(float), stream);

  dim3 grd(NBX, NBY, NCHZ * 2), blk(BLK);

  slab2<0><<<grd, blk, 0, stream>>>(F, M, dF, dM);
  slab2<1><<<grd, blk, 0, stream>>>(dF, dM, pB, nullptr);
  slab1_reduce<<<grd, blk, 0, stream>>>(pB, mask, out);
}

// Round 7
// 186.429 us; speedup vs baseline: 1.8378x; 1.0053x over previous
//
#include <hip/hip_runtime.h>

namespace {

constexpr int LEN   = 160;
constexpr int PLANE = LEN * LEN;            // 25600
constexpr int VOL   = LEN * PLANE;          // 4,096,000 per batch
constexpr float INV_SZ = 1.0f / 125.0f;
constexpr float EPS_   = 1e-10f;

constexpr int TX = 32, TY = 32, ZC = 16;    // 500 blocks
constexpr int RX = TX + 4, RY = TY + 4;     // 36
constexpr int NRAW = RX * RY;               // 1296
constexpr int NCHZ = LEN / ZC;              // 10
constexpr int NBX = LEN / TX, NBY = LEN / TY; // 5 x 5
constexpr int NXY = NBX * NBY;              // 25 tiles per z-slab
constexpr int BLK  = 512;
constexpr int NWG  = NBX * NBY * NCHZ * 2;  // 500
constexpr int QW   = NWG / 8, RW = NWG % 8; // 62, 4 (m204 bijective swizzle)

__device__ __forceinline__ int clampi(int v) {
  return v < 0 ? 0 : (v > LEN - 1 ? LEN - 1 : v);
}

// Bijective XCD swizzle for NWG=500 (m204). Keeps a z-slab's 25 xy-tiles
// (mostly) on one XCD. Perf-only. Measured (R2): FETCH 112->48.5 MB.
struct BlkInfo { int x0, y0, z0; size_t base; };
__device__ __forceinline__ BlkInfo decodeBlock() {
  const int g = blockIdx.x + NBX * (blockIdx.y + NBY * blockIdx.z);
  const int xcd = g & 7, idx = g >> 3;
  const int w = (xcd < RW) ? xcd * (QW + 1) + idx
                           : RW * (QW + 1) + (xcd - RW) * QW + idx;
  const int half = NWG / 2;                 // 250 work items per batch
  const int batch = w / half;
  const int rem   = w % half;
  const int zc = rem / NXY, tl = rem % NXY;
  BlkInfo bi;
  bi.x0 = (tl % NBX) * TX;
  bi.y0 = (tl / NBX) * TY;
  bi.z0 = zc * ZC;
  bi.base = (size_t)batch * VOL;
  return bi;
}

// ---------------------------------------------------------------------------
// R7: stages A+B fused via the variance identity:
//   u = box3(F)/125 ;  sigma^2 = box3(F^2)/125 - u^2   (u const per window)
// One sliding pass computes box-sums of {F, F^2, M, M^2} (squares formed on
// LDS read; x-sum reads amortized across plain+squared) and emits
//   p = ((F-u)/(sF+eps)) * ((M-uM)/(sM+eps))  directly.
// Plane-pair pipelined (R6 structure: 1 barrier/plane, pair prefetch).
// ---------------------------------------------------------------------------
__global__ __launch_bounds__(BLK) void fuseAB(const float* __restrict__ inA,
                                              const float* __restrict__ inB,
                                              float* __restrict__ outP) {
  __shared__ __align__(16) float raw[2][2][RY][RX];   // [field F,M][plane] 20.7KB
  __shared__ __align__(16) float xs [4][2][RY][RX];   // [F,M,F2,M2][plane] 41.5KB

  const int tid = threadIdx.x;
  const BlkInfo bi = decodeBlock();
  const int x0 = bi.x0, y0 = bi.y0, z0 = bi.z0;
  const size_t base = bi.base;

  // plane-invariant halo-load descriptors (3 predicated rounds)
  int off[3], lly[3], llx[3];
  bool act[3];
#pragma unroll
  for (int j = 0; j < 3; ++j) {
    int i = tid + j * BLK;
    act[j] = i < NRAW;
    int ii = act[j] ? i : 0;
    lly[j] = ii / RX; llx[j] = ii % RX;
    off[j] = clampi(y0 - 2 + lly[j]) * LEN + clampi(x0 - 2 + llx[j]);
  }

  const int ly  = tid >> 4;           // 0..31
  const int lx0 = (tid & 15) * 2;     // 0,2,..,30

  float pA[2][3], pB[2][3];           // prefetch pair regs
  float2 rzF[6], rzM[6], rzF2[6], rzM2[6];   // z-rings of xy-sums
  float2 cnF[4], cnM[4];              // center ring (lag 2, pair-push)

  auto loadPair = [&](int t) {
#pragma unroll
    for (int p = 0; p < 2; ++p) {
      const size_t pb = base + (size_t)clampi(t + p) * PLANE;
#pragma unroll
      for (int j = 0; j < 3; ++j)
        if (act[j]) { pA[p][j] = inA[pb + off[j]]; pB[p][j] = inB[pb + off[j]]; }
    }
  };
  auto depositPair = [&]() {
#pragma unroll
    for (int p = 0; p < 2; ++p)
#pragma unroll
      for (int j = 0; j < 3; ++j)
        if (act[j]) {
          raw[0][p][lly[j]][llx[j]] = pA[p][j];
          raw[1][p][lly[j]][llx[j]] = pB[p][j];
        }
  };

  // 4-wide sliding x-sum task: tt in [0,576). Each task reads one field's
  // 8 floats per plane and writes BOTH plain and squared x-sums.
  auto xsumTask = [&](int tt) {
    const int f = tt & 1, c = (tt >> 1) & 7, r = tt >> 4;
#pragma unroll
    for (int p = 0; p < 2; ++p) {
      const float* rp = &raw[f][p][r][4 * c];
      const float4 u = *(const float4*)rp;
      const float4 v = *(const float4*)(rp + 4);
      // plain sliding sums
      const float m = u.y + u.z + u.w;
      float4 s;
      s.x = m + u.x + v.x;
      s.y = m + v.x + v.y;
      s.z = s.y - u.y + v.z;
      s.w = s.z - u.z + v.w;
      *(float4*)&xs[f][p][r][4 * c] = s;
      // squared sliding sums
      float4 uq, vq;
      uq.x = u.x * u.x; uq.y = u.y * u.y; uq.z = u.z * u.z; uq.w = u.w * u.w;
      vq.x = v.x * v.x; vq.y = v.y * v.y; vq.z = v.z * v.z; vq.w = v.w * v.w;
      const float mq = uq.y + uq.z + uq.w;
      float4 q;
      q.x = mq + uq.x + vq.x;
      q.y = mq + vq.x + vq.y;
      q.z = q.y - uq.y + vq.z;
      q.w = q.z - uq.z + vq.w;
      *(float4*)&xs[2 + f][p][r][4 * c] = q;
    }
  };

  loadPair(z0 - 2);
  depositPair();
  __syncthreads();

  for (int t = z0 - 2; t <= z0 + ZC; t += 2) {
    if (t + 2 <= z0 + ZC) loadPair(t + 2);   // prefetch next pair

    xsumTask(tid);
    if (tid < 576 - BLK) xsumTask(tid + BLK);   // 64 extra tasks

    // center ring: shift 2, push cen(t), cen(t+1)
    cnF[0] = cnF[2]; cnF[1] = cnF[3]; cnM[0] = cnM[2]; cnM[1] = cnM[3];
    cnF[2] = *(const float2*)&raw[0][0][ly + 2][lx0 + 2];
    cnF[3] = *(const float2*)&raw[0][1][ly + 2][lx0 + 2];
    cnM[2] = *(const float2*)&raw[1][0][ly + 2][lx0 + 2];
    cnM[3] = *(const float2*)&raw[1][1][ly + 2][lx0 + 2];

    __syncthreads();                        // xs ready; all raw reads done

    if (t + 2 <= z0 + ZC) depositPair();    // raw <- pair (t+2,t+3)

    // z-rings: shift 2, push yd(t), yd(t+1)
#pragma unroll
    for (int s = 0; s < 4; ++s) {
      rzF[s] = rzF[s + 2]; rzM[s] = rzM[s + 2];
      rzF2[s] = rzF2[s + 2]; rzM2[s] = rzM2[s + 2];
    }
#pragma unroll
    for (int p = 0; p < 2; ++p) {
      float2 sf = {0.f, 0.f}, sm = {0.f, 0.f};
      float2 sf2 = {0.f, 0.f}, sm2 = {0.f, 0.f};
#pragma unroll
      for (int k = 0; k < 5; ++k) {
        const float2 a  = *(const float2*)&xs[0][p][ly + k][lx0];
        const float2 b  = *(const float2*)&xs[1][p][ly + k][lx0];
        const float2 a2 = *(const float2*)&xs[2][p][ly + k][lx0];
        const float2 b2 = *(const float2*)&xs[3][p][ly + k][lx0];
        sf.x += a.x;  sf.y += a.y;  sm.x += b.x;  sm.y += b.y;
        sf2.x += a2.x; sf2.y += a2.y; sm2.x += b2.x; sm2.y += b2.y;
      }
      rzF[4 + p] = sf; rzM[4 + p] = sm;
      rzF2[4 + p] = sf2; rzM2[4 + p] = sm2;
    }

    // emit planes zp = t-2, t-1:  p = nF * nM
    if (t >= z0 + 2) {
#pragma unroll
      for (int q = 0; q < 2; ++q) {
        const int zo = t - 2 + q;
        float2 bF = {0.f, 0.f}, bM = {0.f, 0.f};
        float2 bF2 = {0.f, 0.f}, bM2 = {0.f, 0.f};
#pragma unroll
        for (int s = 0; s < 5; ++s) {
          bF.x += rzF[q + s].x;  bF.y += rzF[q + s].y;
          bM.x += rzM[q + s].x;  bM.y += rzM[q + s].y;
          bF2.x += rzF2[q + s].x; bF2.y += rzF2[q + s].y;
          bM2.x += rzM2[q + s].x; bM2.y += rzM2[q + s].y;
        }
        const size_t g = base + (size_t)zo * PLANE + (size_t)(y0 + ly) * LEN + (x0 + lx0);
        float2 o;
        {
          const float uF = bF.x * INV_SZ, uM = bM.x * INV_SZ;
          const float vF = fmaxf(bF2.x * INV_SZ - uF * uF, 0.f);
          const float vM = fmaxf(bM2.x * INV_SZ - uM * uM, 0.f);
          o.x = ((cnF[q].x - uF) / (sqrtf(vF) + EPS_)) *
                ((cnM[q].x - uM) / (sqrtf(vM) + EPS_));
        }
        {
          const float uF = bF.y * INV_SZ, uM = bM.y * INV_SZ;
          const float vF = fmaxf(bF2.y * INV_SZ - uF * uF, 0.f);
          const float vM = fmaxf(bM2.y * INV_SZ - uM * uM, 0.f);
          o.y = ((cnF[q].y - uF) / (sqrtf(vF) + EPS_)) *
                ((cnM[q].y - uM) / (sqrtf(vM) + EPS_));
        }
        *(float2*)&outP[g] = o;
      }
    }
    __syncthreads();                        // raw pair ready; xs reads done
  }
}

// ---------------------------------------------------------------------------
// Stage C: cross = box3(p); acc += cross^2 * mask; block reduce -> atomicAdd.
// Plane-pair pipeline (unchanged from R6, verified).
// ---------------------------------------------------------------------------
__global__ __launch_bounds__(BLK) void slab1_reduce(const float* __restrict__ p,
                                                    const float* __restrict__ mask,
                                                    float* __restrict__ out) {
  __shared__ __align__(16) float raw[2][RY][RX];   // [plane] 10.4KB
  __shared__ __align__(16) float xs [2][RY][RX];   // 10.4KB
  __shared__ float wsum[BLK / 64];

  const int tid = threadIdx.x;
  const BlkInfo bi = decodeBlock();
  const int x0 = bi.x0, y0 = bi.y0, z0 = bi.z0;
  const size_t base = bi.base;

  int off[3], lly[3], llx[3];
  bool act[3];
#pragma unroll
  for (int j = 0; j < 3; ++j) {
    int i = tid + j * BLK;
    act[j] = i < NRAW;
    int ii = act[j] ? i : 0;
    lly[j] = ii / RX; llx[j] = ii % RX;
    off[j] = clampi(y0 - 2 + lly[j]) * LEN + clampi(x0 - 2 + llx[j]);
  }
  const int ly  = tid >> 4;
  const int lx0 = (tid & 15) * 2;

  float pf[2][3];
  float2 rz[6];
  float acc = 0.f;

  auto loadPair = [&](int t) {
#pragma unroll
    for (int pp = 0; pp < 2; ++pp) {
      const size_t pb = base + (size_t)clampi(t + pp) * PLANE;
#pragma unroll
      for (int j = 0; j < 3; ++j)
        if (act[j]) pf[pp][j] = p[pb + off[j]];
    }
  };
  auto depositPair = [&]() {
#pragma unroll
    for (int pp = 0; pp < 2; ++pp)
#pragma unroll
      for (int j = 0; j < 3; ++j)
        if (act[j]) raw[pp][lly[j]][llx[j]] = pf[pp][j];
  };

  loadPair(z0 - 2);
  depositPair();
  __syncthreads();

  for (int t = z0 - 2; t <= z0 + ZC; t += 2) {
    if (t + 2 <= z0 + ZC) loadPair(t + 2);

    if (tid < 288) {                        // x-sum tasks, both planes
      const int c = tid & 7, r = tid >> 3;
#pragma unroll
      for (int pp = 0; pp < 2; ++pp) {
        const float* rp = &raw[pp][r][4 * c];
        const float4 u = *(const float4*)rp;
        const float4 v = *(const float4*)(rp + 4);
        const float m = u.y + u.z + u.w;
        float4 s;
        s.x = m + u.x + v.x;
        s.y = m + v.x + v.y;
        s.z = s.y - u.y + v.z;
        s.w = s.z - u.z + v.w;
        *(float4*)&xs[pp][r][4 * c] = s;
      }
    }
    __syncthreads();

    if (t + 2 <= z0 + ZC) depositPair();

#pragma unroll
    for (int s = 0; s < 4; ++s) rz[s] = rz[s + 2];
#pragma unroll
    for (int pp = 0; pp < 2; ++pp) {
      float2 s2 = {0.f, 0.f};
#pragma unroll
      for (int k = 0; k < 5; ++k) {
        const float2 a = *(const float2*)&xs[pp][ly + k][lx0];
        s2.x += a.x; s2.y += a.y;
      }
      rz[4 + pp] = s2;
    }

    if (t >= z0 + 2) {
#pragma unroll
      for (int q = 0; q < 2; ++q) {
        const int zo = t - 2 + q;
        float2 bs = {0.f, 0.f};
#pragma unroll
        for (int s = 0; s < 5; ++s) { bs.x += rz[q + s].x; bs.y += rz[q + s].y; }
        const size_t g = base + (size_t)zo * PLANE + (size_t)(y0 + ly) * LEN + (x0 + lx0);
        const float2 mk = *(const float2*)&mask[g];
        acc += bs.x * bs.x * mk.x + bs.y * bs.y * mk.y;
      }
    }
    __syncthreads();
  }

#pragma unroll
  for (int o = 32; o > 0; o >>= 1) acc += __shfl_down(acc, o, 64);
  const int lane = tid & 63, wid = tid >> 6;
  if (lane == 0) wsum[wid] = acc;
  __syncthreads();
  if (tid == 0) {
    float t = 0.f;
#pragma unroll
    for (int w = 0; w < BLK / 64; ++w) t += wsum[w];
    atomicAdd(out, -t);
  }
}

}  // namespace

extern "C" void kernel_launch(void* const* d_in, const int* in_sizes, int n_in,
                              void* d_out, int out_size, void* d_ws, size_t ws_size,
                              hipStream_t stream) {
  const float* F    = (const float*)d_in[0];
  const float* M    = (const float*)d_in[1];
  const float* mask = (const float*)d_in[2];
  float* out = (float*)d_out;

  float* pB = (float*)d_ws;   // 2*VOL floats = 32.8 MB

  hipMemsetAsync(d_out, 0, sizeof(float), stream);

  dim3 grd(NBX, NBY, NCHZ * 2), blk(BLK);

  fuseAB<<<grd, blk, 0, stream>>>(F, M, pB);
  slab1_reduce<<<grd, blk, 0, stream>>>(pB, mask, out);
}

// Round 8
// 178.443 us; speedup vs baseline: 1.9200x; 1.0448x over previous
//
#include <hip/hip_runtime.h>

namespace {

constexpr int LEN   = 160;
constexpr int PLANE = LEN * LEN;            // 25600
constexpr int VOL   = LEN * PLANE;          // 4,096,000 per batch
constexpr float INV_SZ = 1.0f / 125.0f;
constexpr float EPS_   = 1e-10f;

constexpr int TX = 32, TY = 16, ZC = 16;    // 1000 blocks, 1 px/thread
constexpr int RX = TX + 4, RY = TY + 4;     // 36, 20
constexpr int NRAW = RX * RY;               // 720
constexpr int NCHZ = LEN / ZC;              // 10
constexpr int NBX = LEN / TX, NBY = LEN / TY; // 5 x 10
constexpr int NXY = NBX * NBY;              // 50 tiles per z-slab
constexpr int BLK  = 512;

__device__ __forceinline__ int clampi(int v) {
  return v < 0 ? 0 : (v > LEN - 1 ? LEN - 1 : v);
}

// XCD swizzle: NWG=1000 = 8 x 125, bijective chunks. Perf-only.
// Measured (R2): FETCH 112->48.5 MB.
struct BlkInfo { int x0, y0, z0; size_t base; };
__device__ __forceinline__ BlkInfo decodeBlock() {
  const int g = blockIdx.x + NBX * (blockIdx.y + NBY * blockIdx.z);
  const int w = (g & 7) * 125 + (g >> 3);
  const int half = NXY * NCHZ;              // 500 work items per batch
  const int batch = w / half;
  const int rem   = w % half;
  const int zc = rem / NXY, tl = rem % NXY;
  BlkInfo bi;
  bi.x0 = (tl % NBX) * TX;
  bi.y0 = (tl / NBX) * TY;
  bi.z0 = zc * ZC;
  bi.base = (size_t)batch * VOL;
  return bi;
}

// ---------------------------------------------------------------------------
// R8: A+B fused (variance identity), plane-pair pipelined, TY=16 and ONE
// pixel per thread. Rationale (R5/R7 evidence): wall = per-wave serial path;
// halving per-thread ownership halves y-sum/ring/emit VALU per wave; rings
// shrink to ~32 floats -> VGPR headroom -> 3-4 blocks/CU. All LDS addresses
// are thread-constant (bases precomputed; reads use immediate offsets).
// ---------------------------------------------------------------------------
__global__ __launch_bounds__(BLK) void fuseAB(const float* __restrict__ inA,
                                              const float* __restrict__ inB,
                                              float* __restrict__ outP) {
  __shared__ __align__(16) float raw[2][2][RY][RX];   // [field][plane] 11.5KB
  __shared__ __align__(16) float xs [4][2][RY][TX];   // [F,M,F2,M2][plane] 20.5KB

  const int tid = threadIdx.x;
  const BlkInfo bi = decodeBlock();
  const int x0 = bi.x0, y0 = bi.y0, z0 = bi.z0;
  const size_t base = bi.base;

  // halo-load descriptors: 2 predicated rounds (NRAW=720)
  int off[2]; float* ldst[2][2][2];  // [round][field][plane] LDS dest
  bool act[2];
#pragma unroll
  for (int j = 0; j < 2; ++j) {
    int i = tid + j * BLK;
    act[j] = i < NRAW;
    int ii = act[j] ? i : 0;
    const int ry = ii / RX, rx = ii % RX;
    off[j] = clampi(y0 - 2 + ry) * LEN + clampi(x0 - 2 + rx);
#pragma unroll
    for (int f = 0; f < 2; ++f)
#pragma unroll
      for (int p = 0; p < 2; ++p) ldst[j][f][p] = &raw[f][p][ry][rx];
  }

  // x-sum task decode, thread-constant: tasks tt in [0,640),
  // tt = p*320 + f*160 + r*8 + c ; thread does tt=tid and (tid<128) tt=tid+512
  const float* tsrc[2]; float* tdst[2]; int ntask = (tid < 128) ? 2 : 1;
#pragma unroll
  for (int k = 0; k < 2; ++k) {
    int tt = (k == 0) ? tid : tid + BLK;
    if (tt >= 640) tt = 0;
    const int p = tt / 320, r1 = tt % 320;
    const int f = r1 / 160, r2 = r1 % 160;
    const int r = r2 / 8,  c = r2 % 8;
    tsrc[k] = &raw[f][p][r][4 * c];
    tdst[k] = &xs[f][p][r][4 * c];
  }
  if (tid >= 128) ntask = 1;

  // owned pixel
  const int ly = tid >> 5, lx = tid & 31;
  const int sOff = (y0 + ly) * LEN + (x0 + lx);
  const float* ybase = &xs[0][0][ly][lx];            // y-sum base (imm offsets)
  constexpr int AS = 2 * RY * TX;                    // array stride (floats)
  constexpr int PS = RY * TX;                        // plane stride

  float pA[2][2], pB[2][2];                          // prefetch regs
  float rzF[6], rzM[6], rzF2[6], rzM2[6];            // z-rings
  float cnF[4], cnM[4];                              // center ring (lag 2)

  auto loadPair = [&](int t) {
#pragma unroll
    for (int p = 0; p < 2; ++p) {
      const size_t pb = base + (size_t)clampi(t + p) * PLANE;
#pragma unroll
      for (int j = 0; j < 2; ++j)
        if (act[j]) { pA[p][j] = inA[pb + off[j]]; pB[p][j] = inB[pb + off[j]]; }
    }
  };
  auto depositPair = [&]() {
#pragma unroll
    for (int p = 0; p < 2; ++p)
#pragma unroll
      for (int j = 0; j < 2; ++j)
        if (act[j]) { *ldst[j][0][p] = pA[p][j]; *ldst[j][1][p] = pB[p][j]; }
  };

  auto xsumTask = [&](int k) {
    const float4 u = *(const float4*)tsrc[k];
    const float4 v = *(const float4*)(tsrc[k] + 4);
    const float m = u.y + u.z + u.w;
    float4 s;
    s.x = m + u.x + v.x;
    s.y = m + v.x + v.y;
    s.z = s.y - u.y + v.z;
    s.w = s.z - u.z + v.w;
    *(float4*)tdst[k] = s;
    float4 uq, vq;
    uq.x = u.x * u.x; uq.y = u.y * u.y; uq.z = u.z * u.z; uq.w = u.w * u.w;
    vq.x = v.x * v.x; vq.y = v.y * v.y; vq.z = v.z * v.z; vq.w = v.w * v.w;
    const float mq = uq.y + uq.z + uq.w;
    float4 q;
    q.x = mq + uq.x + vq.x;
    q.y = mq + vq.x + vq.y;
    q.z = q.y - uq.y + vq.z;
    q.w = q.z - uq.z + vq.w;
    *(float4*)(tdst[k] + 2 * AS) = q;
  };

  loadPair(z0 - 2);
  depositPair();
  __syncthreads();

  for (int t = z0 - 2; t <= z0 + ZC; t += 2) {
    if (t + 2 <= z0 + ZC) loadPair(t + 2);   // prefetch next pair

    xsumTask(0);
    if (ntask == 2) xsumTask(1);

    // center ring: shift 2, push cen(t), cen(t+1)
    cnF[0] = cnF[2]; cnF[1] = cnF[3]; cnM[0] = cnM[2]; cnM[1] = cnM[3];
    cnF[2] = raw[0][0][ly + 2][lx + 2];
    cnF[3] = raw[0][1][ly + 2][lx + 2];
    cnM[2] = raw[1][0][ly + 2][lx + 2];
    cnM[3] = raw[1][1][ly + 2][lx + 2];

    __syncthreads();                        // xs ready; all raw reads done

    if (t + 2 <= z0 + ZC) depositPair();    // raw <- pair (t+2,t+3)

    // z-rings: shift 2, push yd(t), yd(t+1)  [rz[k] = yd(t-4+k)]
#pragma unroll
    for (int s = 0; s < 4; ++s) {
      rzF[s] = rzF[s + 2]; rzM[s] = rzM[s + 2];
      rzF2[s] = rzF2[s + 2]; rzM2[s] = rzM2[s + 2];
    }
#pragma unroll
    for (int p = 0; p < 2; ++p) {
      float sf = 0.f, sm = 0.f, sf2 = 0.f, sm2 = 0.f;
#pragma unroll
      for (int k = 0; k < 5; ++k) {
        sf  += ybase[0 * AS + p * PS + k * TX];
        sm  += ybase[1 * AS + p * PS + k * TX];
        sf2 += ybase[2 * AS + p * PS + k * TX];
        sm2 += ybase[3 * AS + p * PS + k * TX];
      }
      rzF[4 + p] = sf; rzM[4 + p] = sm;
      rzF2[4 + p] = sf2; rzM2[4 + p] = sm2;
    }

    // emit planes zo = t-2, t-1:  p = nF * nM
    if (t >= z0 + 2) {
#pragma unroll
      for (int q = 0; q < 2; ++q) {
        const int zo = t - 2 + q;
        float bF = 0.f, bM = 0.f, bF2 = 0.f, bM2 = 0.f;
#pragma unroll
        for (int s = 0; s < 5; ++s) {
          bF += rzF[q + s]; bM += rzM[q + s];
          bF2 += rzF2[q + s]; bM2 += rzM2[q + s];
        }
        const float uF = bF * INV_SZ, uM = bM * INV_SZ;
        const float vF = fmaxf(bF2 * INV_SZ - uF * uF, 0.f);
        const float vM = fmaxf(bM2 * INV_SZ - uM * uM, 0.f);
        const float o = ((cnF[q] - uF) / (sqrtf(vF) + EPS_)) *
                        ((cnM[q] - uM) / (sqrtf(vM) + EPS_));
        outP[base + (size_t)zo * PLANE + sOff] = o;
      }
    }
    __syncthreads();                        // raw pair ready; xs reads done
  }
}

// ---------------------------------------------------------------------------
// Stage C: cross = box3(p); acc += cross^2 * mask; block reduce -> atomicAdd.
// Same TY=16 / 1 px-per-thread / pair structure. LDS ~11KB -> 4 blocks/CU.
// ---------------------------------------------------------------------------
__global__ __launch_bounds__(BLK) void slab1_reduce(const float* __restrict__ p,
                                                    const float* __restrict__ mask,
                                                    float* __restrict__ out) {
  __shared__ __align__(16) float raw[2][RY][RX];   // [plane] 5.8KB
  __shared__ __align__(16) float xs [2][RY][TX];   // 5.1KB
  __shared__ float wsum[BLK / 64];

  const int tid = threadIdx.x;
  const BlkInfo bi = decodeBlock();
  const int x0 = bi.x0, y0 = bi.y0, z0 = bi.z0;
  const size_t base = bi.base;

  int off[2]; float* ldst[2][2];
  bool act[2];
#pragma unroll
  for (int j = 0; j < 2; ++j) {
    int i = tid + j * BLK;
    act[j] = i < NRAW;
    int ii = act[j] ? i : 0;
    const int ry = ii / RX, rx = ii % RX;
    off[j] = clampi(y0 - 2 + ry) * LEN + clampi(x0 - 2 + rx);
#pragma unroll
    for (int pp = 0; pp < 2; ++pp) ldst[j][pp] = &raw[pp][ry][rx];
  }

  // x-sum task (tasks tt in [0,320): tt = p*160 + r*8 + c), one per thread
  const bool tact = tid < 320;
  const float* tsrc; float* tdst;
  {
    int tt = tact ? tid : 0;
    const int pp = tt / 160, r1 = tt % 160;
    const int r = r1 / 8, c = r1 % 8;
    tsrc = &raw[pp][r][4 * c];
    tdst = &xs[pp][r][4 * c];
  }

  const int ly = tid >> 5, lx = tid & 31;
  const int sOff = (y0 + ly) * LEN + (x0 + lx);
  const float* ybase = &xs[0][ly][lx];
  constexpr int PS = RY * TX;

  float pf[2][2];
  float rz[6];
  float acc = 0.f;

  auto loadPair = [&](int t) {
#pragma unroll
    for (int pp = 0; pp < 2; ++pp) {
      const size_t pb = base + (size_t)clampi(t + pp) * PLANE;
#pragma unroll
      for (int j = 0; j < 2; ++j)
        if (act[j]) pf[pp][j] = p[pb + off[j]];
    }
  };
  auto depositPair = [&]() {
#pragma unroll
    for (int pp = 0; pp < 2; ++pp)
#pragma unroll
      for (int j = 0; j < 2; ++j)
        if (act[j]) *ldst[j][pp] = pf[pp][j];
  };

  loadPair(z0 - 2);
  depositPair();
  __syncthreads();

  for (int t = z0 - 2; t <= z0 + ZC; t += 2) {
    if (t + 2 <= z0 + ZC) loadPair(t + 2);

    if (tact) {
      const float4 u = *(const float4*)tsrc;
      const float4 v = *(const float4*)(tsrc + 4);
      const float m = u.y + u.z + u.w;
      float4 s;
      s.x = m + u.x + v.x;
      s.y = m + v.x + v.y;
      s.z = s.y - u.y + v.z;
      s.w = s.z - u.z + v.w;
      *(float4*)tdst = s;
    }
    __syncthreads();

    if (t + 2 <= z0 + ZC) depositPair();

#pragma unroll
    for (int s = 0; s < 4; ++s) rz[s] = rz[s + 2];
#pragma unroll
    for (int pp = 0; pp < 2; ++pp) {
      float s2 = 0.f;
#pragma unroll
      for (int k = 0; k < 5; ++k) s2 += ybase[pp * PS + k * TX];
      rz[4 + pp] = s2;
    }

    if (t >= z0 + 2) {
#pragma unroll
      for (int q = 0; q < 2; ++q) {
        const int zo = t - 2 + q;
        float bs = 0.f;
#pragma unroll
        for (int s = 0; s < 5; ++s) bs += rz[q + s];
        const size_t g = base + (size_t)zo * PLANE + sOff;
        acc += bs * bs * mask[g];
      }
    }
    __syncthreads();
  }

#pragma unroll
  for (int o = 32; o > 0; o >>= 1) acc += __shfl_down(acc, o, 64);
  const int lane = tid & 63, wid = tid >> 6;
  if (lane == 0) wsum[wid] = acc;
  __syncthreads();
  if (tid == 0) {
    float tt = 0.f;
#pragma unroll
    for (int w = 0; w < BLK / 64; ++w) tt += wsum[w];
    atomicAdd(out, -tt);
  }
}

}  // namespace

extern "C" void kernel_launch(void* const* d_in, const int* in_sizes, int n_in,
                              void* d_out, int out_size, void* d_ws, size_t ws_size,
                              hipStream_t stream) {
  const float* F    = (const float*)d_in[0];
  const float* M    = (const float*)d_in[1];
  const float* mask = (const float*)d_in[2];
  float* out = (float*)d_out;

  float* pB = (float*)d_ws;   // 2*VOL floats = 32.8 MB

  hipMemsetAsync(d_out, 0, sizeof(float), stream);

  dim3 grd(NBX, NBY, NCHZ * 2), blk(BLK);

  fuseAB<<<grd, blk, 0, stream>>>(F, M, pB);
  slab1_reduce<<<grd, blk, 0, stream>>>(pB, mask, out);
}

// Round 9
// 163.343 us; speedup vs baseline: 2.0975x; 1.0924x over previous
//
#include <hip/hip_runtime.h>

namespace {

constexpr int LEN   = 160;
constexpr int PLANE = LEN * LEN;            // 25600
constexpr int VOL   = LEN * PLANE;          // 4,096,000 per batch
constexpr float INV_SZ = 1.0f / 125.0f;
constexpr float EPS_   = 1e-10f;

constexpr int BLK = 512;

// fuseAB geometry: 32x16 tile, ZC=32 -> 500 blocks (2/CU resident)
constexpr int FTX = 32, FTY = 16, FZC = 32;
constexpr int FRX = FTX + 4, FRY = FTY + 4;   // 36, 20
constexpr int FNRAW = FRX * FRY;              // 720
constexpr int FNBX = 5, FNBY = 10, FNXY = 50, FNCHZ = 5;

// slab1 geometry: 32x32 tile, ZC=16 -> 500 blocks (R6-proven)
constexpr int STX = 32, STY = 32, SZC = 16;
constexpr int SRX = STX + 4, SRY = STY + 4;   // 36, 36
constexpr int SNRAW = SRX * SRY;              // 1296
constexpr int SNBX = 5, SNBY = 5, SNXY = 25, SNCHZ = 10;

constexpr int NWG = 500, QW = 62, RW = 4;     // m204 bijective XCD swizzle

__device__ __forceinline__ int clampi(int v) {
  return v < 0 ? 0 : (v > LEN - 1 ? LEN - 1 : v);
}

// Bijective XCD swizzle for 500 blocks (m204). Perf-only.
// Measured (R2): FETCH 112 -> 48.5 MB.
__device__ __forceinline__ int swz(int g) {
  const int xcd = g & 7, idx = g >> 3;
  return (xcd < RW) ? xcd * (QW + 1) + idx
                    : RW * (QW + 1) + (xcd - RW) * QW + idx;
}

// ---------------------------------------------------------------------------
// R9 fuseAB: A+B fused (variance identity), plane-pair pipelined.
// y/emit phase on 256 threads with 2 px each (ds_read_b64, float2 rings):
// y-phase LDS wave-instr halves (R8 accounting: LDS pipe 75% busy, y-phase
// was 1860 of 2900 cyc/slot). Emit uses one division per px per plane.
// ZC=32: 500 blocks = 2/CU exactly at ~90 VGPR; z-amp 1.19.
// ---------------------------------------------------------------------------
__global__ __launch_bounds__(BLK) void fuseAB(const float* __restrict__ inA,
                                              const float* __restrict__ inB,
                                              float* __restrict__ outP) {
  __shared__ __align__(16) float raw[2][2][FRY][FRX];   // [field][plane] 11.5KB
  __shared__ __align__(16) float xs [4][2][FRY][FTX];   // [F,M,F2,M2][plane] 20.5KB

  const int tid = threadIdx.x;
  const int g = blockIdx.x + FNBX * (blockIdx.y + FNBY * blockIdx.z);
  const int w = swz(g);
  const int batch = w / 250, rem = w % 250;
  const int zc = rem / FNXY, tl = rem % FNXY;
  const int x0 = (tl % FNBX) * FTX;
  const int y0 = (tl / FNBX) * FTY;
  const int z0 = zc * FZC;
  const size_t base = (size_t)batch * VOL;

  // halo-load descriptors: 2 predicated rounds (FNRAW=720; round 1: tid<208)
  int off[2]; float* ldst[2][2][2];  // [round][field][plane]
  bool act[2];
#pragma unroll
  for (int j = 0; j < 2; ++j) {
    int i = tid + j * BLK;
    act[j] = i < FNRAW;
    int ii = act[j] ? i : 0;
    const int ry = ii / FRX, rx = ii % FRX;
    off[j] = clampi(y0 - 2 + ry) * LEN + clampi(x0 - 2 + rx);
#pragma unroll
    for (int f = 0; f < 2; ++f)
#pragma unroll
      for (int p = 0; p < 2; ++p) ldst[j][f][p] = &raw[f][p][ry][rx];
  }

  // x-sum task decode: tt in [0,640), tt = p*320 + f*160 + r*8 + c
  const float* tsrc[2]; float* tdst[2];
#pragma unroll
  for (int k = 0; k < 2; ++k) {
    int tt = (k == 0) ? tid : tid + BLK;
    if (tt >= 640) tt = 0;
    const int p = tt / 320, r1 = tt % 320;
    const int f = r1 / 160, r2 = r1 % 160;
    const int r = r2 / 8,  c = r2 % 8;
    tsrc[k] = &raw[f][p][r][4 * c];
    tdst[k] = &xs[f][p][r][4 * c];
  }

  // y/emit ownership: threads 0..255 own 2 adjacent px
  const bool qact = tid < 256;
  const int ly  = tid >> 4;           // 0..15
  const int lx0 = (tid & 15) * 2;     // 0,2,..,30
  const int sOff = (y0 + ly) * LEN + (x0 + lx0);

  float pA[2][2], pB[2][2];                 // prefetch regs
  float2 rzF[6], rzM[6], rzF2[6], rzM2[6];  // z-rings (float2 = 2 px)
  float2 cnF[4], cnM[4];                    // center ring (lag 2)

  auto loadPair = [&](int t) {
#pragma unroll
    for (int p = 0; p < 2; ++p) {
      const size_t pb = base + (size_t)clampi(t + p) * PLANE;
#pragma unroll
      for (int j = 0; j < 2; ++j)
        if (act[j]) { pA[p][j] = inA[pb + off[j]]; pB[p][j] = inB[pb + off[j]]; }
    }
  };
  auto depositPair = [&]() {
#pragma unroll
    for (int p = 0; p < 2; ++p)
#pragma unroll
      for (int j = 0; j < 2; ++j)
        if (act[j]) { *ldst[j][0][p] = pA[p][j]; *ldst[j][1][p] = pB[p][j]; }
  };

  auto xsumTask = [&](int k) {
    const float4 u = *(const float4*)tsrc[k];
    const float4 v = *(const float4*)(tsrc[k] + 4);
    const float m = u.y + u.z + u.w;
    float4 s;
    s.x = m + u.x + v.x;
    s.y = m + v.x + v.y;
    s.z = s.y - u.y + v.z;
    s.w = s.z - u.z + v.w;
    *(float4*)tdst[k] = s;
    float4 uq, vq;
    uq.x = u.x * u.x; uq.y = u.y * u.y; uq.z = u.z * u.z; uq.w = u.w * u.w;
    vq.x = v.x * v.x; vq.y = v.y * v.y; vq.z = v.z * v.z; vq.w = v.w * v.w;
    const float mq = uq.y + uq.z + uq.w;
    float4 q;
    q.x = mq + uq.x + vq.x;
    q.y = mq + vq.x + vq.y;
    q.z = q.y - uq.y + vq.z;
    q.w = q.z - uq.z + vq.w;
    *(float4*)(tdst[k] + 2 * 2 * FRY * FTX) = q;   // +2 field-arrays
  };

  loadPair(z0 - 2);
  depositPair();
  __syncthreads();

  for (int t = z0 - 2; t <= z0 + FZC; t += 2) {
    if (t + 2 <= z0 + FZC) loadPair(t + 2);   // prefetch next pair

    xsumTask(0);
    if (tid < 128) xsumTask(1);

    if (qact) {
      // center ring: shift 2, push cen(t), cen(t+1)
      cnF[0] = cnF[2]; cnF[1] = cnF[3]; cnM[0] = cnM[2]; cnM[1] = cnM[3];
      cnF[2] = *(const float2*)&raw[0][0][ly + 2][lx0 + 2];
      cnF[3] = *(const float2*)&raw[0][1][ly + 2][lx0 + 2];
      cnM[2] = *(const float2*)&raw[1][0][ly + 2][lx0 + 2];
      cnM[3] = *(const float2*)&raw[1][1][ly + 2][lx0 + 2];
    }

    __syncthreads();                        // xs ready; all raw reads done

    if (t + 2 <= z0 + FZC) depositPair();   // raw <- pair (t+2,t+3)

    if (qact) {
      // z-rings: shift 2, push yd(t), yd(t+1)
#pragma unroll
      for (int s = 0; s < 4; ++s) {
        rzF[s] = rzF[s + 2]; rzM[s] = rzM[s + 2];
        rzF2[s] = rzF2[s + 2]; rzM2[s] = rzM2[s + 2];
      }
#pragma unroll
      for (int p = 0; p < 2; ++p) {
        float2 sf = {0.f, 0.f}, sm = {0.f, 0.f};
        float2 sf2 = {0.f, 0.f}, sm2 = {0.f, 0.f};
#pragma unroll
        for (int k = 0; k < 5; ++k) {
          const float2 a  = *(const float2*)&xs[0][p][ly + k][lx0];
          const float2 b  = *(const float2*)&xs[1][p][ly + k][lx0];
          const float2 a2 = *(const float2*)&xs[2][p][ly + k][lx0];
          const float2 b2 = *(const float2*)&xs[3][p][ly + k][lx0];
          sf.x += a.x;   sf.y += a.y;   sm.x += b.x;   sm.y += b.y;
          sf2.x += a2.x; sf2.y += a2.y; sm2.x += b2.x; sm2.y += b2.y;
        }
        rzF[4 + p] = sf; rzM[4 + p] = sm;
        rzF2[4 + p] = sf2; rzM2[4 + p] = sm2;
      }

      // emit planes zo = t-2, t-1:  p = nF * nM  (single division)
      if (t >= z0 + 2) {
#pragma unroll
        for (int q = 0; q < 2; ++q) {
          const int zo = t - 2 + q;
          float2 bF = {0.f, 0.f}, bM = {0.f, 0.f};
          float2 bF2 = {0.f, 0.f}, bM2 = {0.f, 0.f};
#pragma unroll
          for (int s = 0; s < 5; ++s) {
            bF.x += rzF[q + s].x;   bF.y += rzF[q + s].y;
            bM.x += rzM[q + s].x;   bM.y += rzM[q + s].y;
            bF2.x += rzF2[q + s].x; bF2.y += rzF2[q + s].y;
            bM2.x += rzM2[q + s].x; bM2.y += rzM2[q + s].y;
          }
          float2 o;
          {
            const float uF = bF.x * INV_SZ, uM = bM.x * INV_SZ;
            const float vF = fmaxf(bF2.x * INV_SZ - uF * uF, 0.f);
            const float vM = fmaxf(bM2.x * INV_SZ - uM * uM, 0.f);
            o.x = ((cnF[q].x - uF) * (cnM[q].x - uM)) /
                  ((sqrtf(vF) + EPS_) * (sqrtf(vM) + EPS_));
          }
          {
            const float uF = bF.y * INV_SZ, uM = bM.y * INV_SZ;
            const float vF = fmaxf(bF2.y * INV_SZ - uF * uF, 0.f);
            const float vM = fmaxf(bM2.y * INV_SZ - uM * uM, 0.f);
            o.y = ((cnF[q].y - uF) * (cnM[q].y - uM)) /
                  ((sqrtf(vF) + EPS_) * (sqrtf(vM) + EPS_));
          }
          *(float2*)&outP[base + (size_t)zo * PLANE + sOff] = o;
        }
      }
    }
    __syncthreads();                        // raw pair ready; xs reads done
  }
}

// ---------------------------------------------------------------------------
// Stage C (R6-proven TY=32 plane-pair version): cross = box3(p);
// acc += cross^2 * mask; block reduce -> atomicAdd.
// ---------------------------------------------------------------------------
__global__ __launch_bounds__(BLK) void slab1_reduce(const float* __restrict__ p,
                                                    const float* __restrict__ mask,
                                                    float* __restrict__ out) {
  __shared__ __align__(16) float raw[2][SRY][SRX];   // [plane] 10.4KB
  __shared__ __align__(16) float xs [2][SRY][SRX];   // 10.4KB
  __shared__ float wsum[BLK / 64];

  const int tid = threadIdx.x;
  const int g = blockIdx.x + SNBX * (blockIdx.y + SNBY * blockIdx.z);
  const int w = swz(g);
  const int batch = w / 250, rem = w % 250;
  const int zc = rem / SNXY, tl = rem % SNXY;
  const int x0 = (tl % SNBX) * STX;
  const int y0 = (tl / SNBX) * STY;
  const int z0 = zc * SZC;
  const size_t base = (size_t)batch * VOL;

  int off[3], lly[3], llx[3];
  bool act[3];
#pragma unroll
  for (int j = 0; j < 3; ++j) {
    int i = tid + j * BLK;
    act[j] = i < SNRAW;
    int ii = act[j] ? i : 0;
    lly[j] = ii / SRX; llx[j] = ii % SRX;
    off[j] = clampi(y0 - 2 + lly[j]) * LEN + clampi(x0 - 2 + llx[j]);
  }
  const int ly  = tid >> 4;
  const int lx0 = (tid & 15) * 2;

  float pf[2][3];
  float2 rz[6];
  float acc = 0.f;

  auto loadPair = [&](int t) {
#pragma unroll
    for (int pp = 0; pp < 2; ++pp) {
      const size_t pb = base + (size_t)clampi(t + pp) * PLANE;
#pragma unroll
      for (int j = 0; j < 3; ++j)
        if (act[j]) pf[pp][j] = p[pb + off[j]];
    }
  };
  auto depositPair = [&]() {
#pragma unroll
    for (int pp = 0; pp < 2; ++pp)
#pragma unroll
      for (int j = 0; j < 3; ++j)
        if (act[j]) raw[pp][lly[j]][llx[j]] = pf[pp][j];
  };

  loadPair(z0 - 2);
  depositPair();
  __syncthreads();

  for (int t = z0 - 2; t <= z0 + SZC; t += 2) {
    if (t + 2 <= z0 + SZC) loadPair(t + 2);

    if (tid < 288) {                        // x-sum tasks, both planes
      const int c = tid & 7, r = tid >> 3;
#pragma unroll
      for (int pp = 0; pp < 2; ++pp) {
        const float* rp = &raw[pp][r][4 * c];
        const float4 u = *(const float4*)rp;
        const float4 v = *(const float4*)(rp + 4);
        const float m = u.y + u.z + u.w;
        float4 s;
        s.x = m + u.x + v.x;
        s.y = m + v.x + v.y;
        s.z = s.y - u.y + v.z;
        s.w = s.z - u.z + v.w;
        *(float4*)&xs[pp][r][4 * c] = s;
      }
    }
    __syncthreads();

    if (t + 2 <= z0 + SZC) depositPair();

#pragma unroll
    for (int s = 0; s < 4; ++s) rz[s] = rz[s + 2];
#pragma unroll
    for (int pp = 0; pp < 2; ++pp) {
      float2 s2 = {0.f, 0.f};
#pragma unroll
      for (int k = 0; k < 5; ++k) {
        const float2 a = *(const float2*)&xs[pp][ly + k][lx0];
        s2.x += a.x; s2.y += a.y;
      }
      rz[4 + pp] = s2;
    }

    if (t >= z0 + 2) {
#pragma unroll
      for (int q = 0; q < 2; ++q) {
        const int zo = t - 2 + q;
        float2 bs = {0.f, 0.f};
#pragma unroll
        for (int s = 0; s < 5; ++s) { bs.x += rz[q + s].x; bs.y += rz[q + s].y; }
        const size_t gg = base + (size_t)zo * PLANE + (size_t)(y0 + ly) * LEN + (x0 + lx0);
        const float2 mk = *(const float2*)&mask[gg];
        acc += bs.x * bs.x * mk.x + bs.y * bs.y * mk.y;
      }
    }
    __syncthreads();
  }

#pragma unroll
  for (int o = 32; o > 0; o >>= 1) acc += __shfl_down(acc, o, 64);
  const int lane = tid & 63, wid = tid >> 6;
  if (lane == 0) wsum[wid] = acc;
  __syncthreads();
  if (tid == 0) {
    float tt = 0.f;
#pragma unroll
    for (int ww = 0; ww < BLK / 64; ++ww) tt += wsum[ww];
    atomicAdd(out, -tt);
  }
}

}  // namespace

extern "C" void kernel_launch(void* const* d_in, const int* in_sizes, int n_in,
                              void* d_out, int out_size, void* d_ws, size_t ws_size,
                              hipStream_t stream) {
  const float* F    = (const float*)d_in[0];
  const float* M    = (const float*)d_in[1];
  const float* mask = (const float*)d_in[2];
  float* out = (float*)d_out;

  float* pB = (float*)d_ws;   // 2*VOL floats = 32.8 MB

  hipMemsetAsync(d_out, 0, sizeof(float), stream);

  dim3 gf(FNBX, FNBY, FNCHZ * 2), blk(BLK);   // 5 x 10 x 10 = 500
  dim3 gs(SNBX, SNBY, SNCHZ * 2);             // 5 x  5 x 20 = 500

  fuseAB<<<gf, blk, 0, stream>>>(F, M, pB);
  slab1_reduce<<<gs, blk, 0, stream>>>(pB, mask, out);
}

// Round 10
// 162.847 us; speedup vs baseline: 2.1039x; 1.0030x over previous
//
#include <hip/hip_runtime.h>

namespace {

constexpr int LEN   = 160;
constexpr int PLANE = LEN * LEN;            // 25600
constexpr int VOL   = LEN * PLANE;          // 4,096,000 per batch
constexpr float INV_SZ = 1.0f / 125.0f;
constexpr float EPS_   = 1e-10f;

constexpr int BLK = 512;

// fuseAB geometry: 32x16 tile, ZC=32 -> 500 blocks
constexpr int FTX = 32, FTY = 16, FZC = 32;
constexpr int FRX = FTX + 4, FRY = FTY + 4;   // 36, 20
constexpr int FNRAW = FRX * FRY;              // 720
constexpr int FNBX = 5, FNBY = 10, FNXY = 50, FNCHZ = 5;

// slab1 geometry: 32x32 tile, ZC=16 -> 500 blocks
constexpr int STX = 32, STY = 32, SZC = 16;
constexpr int SRX = STX + 4, SRY = STY + 4;   // 36, 36
constexpr int SNRAW = SRX * SRY;              // 1296
constexpr int SNBX = 5, SNBY = 5, SNXY = 25, SNCHZ = 10;

constexpr int QW = 62, RW = 4;                // m204 bijective XCD swizzle (500)

__device__ __forceinline__ int clampi(int v) {
  return v < 0 ? 0 : (v > LEN - 1 ? LEN - 1 : v);
}

__device__ __forceinline__ int swz(int g) {
  const int xcd = g & 7, idx = g >> 3;
  return (xcd < RW) ? xcd * (QW + 1) + idx
                    : RW * (QW + 1) + (xcd - RW) * QW + idx;
}

// ---------------------------------------------------------------------------
// R10 fuseAB: A+B fused (variance identity), plane-pair pipelined, ONE
// barrier per pair-iter (was 2). raw and xs double-buffered by iteration
// parity; z-loop unrolled x2 so buf index is compile-time (LDS imm offsets).
// Deposit is 1-iter delayed (ping-pong reg sets) -> global load->use distance
// = one full iteration. R9 accounting: 2 barriers cost ~1300 of 3100 cyc/slot.
// Handoffs: every LDS write->read crosses exactly one barrier (audited).
// ---------------------------------------------------------------------------
__global__ __launch_bounds__(BLK) void fuseAB(const float* __restrict__ inA,
                                              const float* __restrict__ inB,
                                              float* __restrict__ outP) {
  __shared__ __align__(16) float raw[2][2][2][FRY][FRX];  // [buf][field][plane] 23KB
  __shared__ __align__(16) float xs [2][4][2][FRY][FTX];  // [buf][arr][plane] 41KB
  constexpr int RAWB = 2 * 2 * FRY * FRX;   // floats per raw buf (2880)
  constexpr int XSB  = 4 * 2 * FRY * FTX;   // floats per xs buf (5120)
  constexpr int AS   = 2 * FRY * FTX;       // xs array stride (1280)
  constexpr int PS   = FRY * FTX;           // xs plane stride (640)

  const int tid = threadIdx.x;
  const int g = blockIdx.x + FNBX * (blockIdx.y + FNBY * blockIdx.z);
  const int w = swz(g);
  const int batch = w / 250, rem = w % 250;
  const int zc = rem / FNXY, tl = rem % FNXY;
  const int x0 = (tl % FNBX) * FTX;
  const int y0 = (tl / FNBX) * FTY;
  const int z0 = zc * FZC;
  const size_t base = (size_t)batch * VOL;

  // halo-load descriptors (buf0 pointers; buf1 = +RAWB)
  int off[2]; float* ld0[2][2][2];  // [round][field][plane]
  bool act[2];
#pragma unroll
  for (int j = 0; j < 2; ++j) {
    int i = tid + j * BLK;
    act[j] = i < FNRAW;
    int ii = act[j] ? i : 0;
    const int ry = ii / FRX, rx = ii % FRX;
    off[j] = clampi(y0 - 2 + ry) * LEN + clampi(x0 - 2 + rx);
#pragma unroll
    for (int f = 0; f < 2; ++f)
#pragma unroll
      for (int p = 0; p < 2; ++p) ld0[j][f][p] = &raw[0][f][p][ry][rx];
  }

  // x-sum task decode (buf0 pointers): tt in [0,640), tt = p*320+f*160+r*8+c
  const float* ts0[2]; float* td0[2];
#pragma unroll
  for (int k = 0; k < 2; ++k) {
    int tt = (k == 0) ? tid : tid + BLK;
    if (tt >= 640) tt = 0;
    const int p = tt / 320, r1 = tt % 320;
    const int f = r1 / 160, r2 = r1 % 160;
    const int r = r2 / 8,  c = r2 % 8;
    ts0[k] = &raw[0][f][p][r][4 * c];
    td0[k] = &xs[0][f][p][r][4 * c];
  }

  // y/emit ownership: threads 0..255 own 2 adjacent px
  const bool qact = tid < 256;
  const int ly  = tid >> 4;           // 0..15
  const int lx0 = (tid & 15) * 2;
  const int sOff = (y0 + ly) * LEN + (x0 + lx0);
  const float* yb0 = &xs[0][0][0][ly][lx0];

  float s0A[2][2], s0B[2][2], s1A[2][2], s1B[2][2];  // ping-pong prefetch
  float2 rzF[6], rzM[6], rzF2[6], rzM2[6];           // z-rings
  float2 cnF[4], cnM[4];                             // center ring (lag 2)

  auto loadPair = [&](int t, float (&ra)[2][2], float (&rb)[2][2]) {
#pragma unroll
    for (int p = 0; p < 2; ++p) {
      const size_t pb = base + (size_t)clampi(t + p) * PLANE;
#pragma unroll
      for (int j = 0; j < 2; ++j)
        if (act[j]) { ra[p][j] = inA[pb + off[j]]; rb[p][j] = inB[pb + off[j]]; }
    }
  };
  auto depositPair = [&](int buf, float (&ra)[2][2], float (&rb)[2][2]) {
#pragma unroll
    for (int p = 0; p < 2; ++p)
#pragma unroll
      for (int j = 0; j < 2; ++j)
        if (act[j]) {
          ld0[j][0][p][buf * RAWB] = ra[p][j];
          ld0[j][1][p][buf * RAWB] = rb[p][j];
        }
  };

  auto xsumTask = [&](int buf, int k) {
    const float* src = ts0[k] + buf * RAWB;
    float* dst = td0[k] + buf * XSB;
    const float4 u = *(const float4*)src;
    const float4 v = *(const float4*)(src + 4);
    const float m = u.y + u.z + u.w;
    float4 s;
    s.x = m + u.x + v.x;
    s.y = m + v.x + v.y;
    s.z = s.y - u.y + v.z;
    s.w = s.z - u.z + v.w;
    *(float4*)dst = s;
    float4 uq, vq;
    uq.x = u.x * u.x; uq.y = u.y * u.y; uq.z = u.z * u.z; uq.w = u.w * u.w;
    vq.x = v.x * v.x; vq.y = v.y * v.y; vq.z = v.z * v.z; vq.w = v.w * v.w;
    const float mq = uq.y + uq.z + uq.w;
    float4 q;
    q.x = mq + uq.x + vq.x;
    q.y = mq + vq.x + vq.y;
    q.z = q.y - uq.y + vq.z;
    q.w = q.z - uq.z + vq.w;
    *(float4*)(dst + 2 * AS) = q;   // squared arrays live +2 array-slots up
  };

  // one pair-iteration; buf is a compile-time literal at each call site
  auto body = [&](int buf, int t,
                  float (&dA)[2][2], float (&dB)[2][2],
                  float (&lA)[2][2], float (&lB)[2][2]) {
    if (t + 2 <= z0 + FZC) depositPair(buf ^ 1, dA, dB);  // pair(t+2)
    if (t + 4 <= z0 + FZC) loadPair(t + 4, lA, lB);       // fire & forget

    xsumTask(buf, 0);
    if (tid < 128) xsumTask(buf, 1);

    if (qact) {
      cnF[0] = cnF[2]; cnF[1] = cnF[3]; cnM[0] = cnM[2]; cnM[1] = cnM[3];
      cnF[2] = *(const float2*)&raw[buf][0][0][ly + 2][lx0 + 2];
      cnF[3] = *(const float2*)&raw[buf][0][1][ly + 2][lx0 + 2];
      cnM[2] = *(const float2*)&raw[buf][1][0][ly + 2][lx0 + 2];
      cnM[3] = *(const float2*)&raw[buf][1][1][ly + 2][lx0 + 2];
    }

    __syncthreads();   // the ONLY barrier this iteration

    if (qact) {
#pragma unroll
      for (int s = 0; s < 4; ++s) {
        rzF[s] = rzF[s + 2]; rzM[s] = rzM[s + 2];
        rzF2[s] = rzF2[s + 2]; rzM2[s] = rzM2[s + 2];
      }
      const float* yb = yb0 + buf * XSB;
#pragma unroll
      for (int p = 0; p < 2; ++p) {
        float2 sf = {0.f, 0.f}, sm = {0.f, 0.f};
        float2 sf2 = {0.f, 0.f}, sm2 = {0.f, 0.f};
#pragma unroll
        for (int k = 0; k < 5; ++k) {
          const float2 a  = *(const float2*)(yb + 0 * AS + p * PS + k * FTX);
          const float2 b  = *(const float2*)(yb + 1 * AS + p * PS + k * FTX);
          const float2 a2 = *(const float2*)(yb + 2 * AS + p * PS + k * FTX);
          const float2 b2 = *(const float2*)(yb + 3 * AS + p * PS + k * FTX);
          sf.x += a.x;   sf.y += a.y;   sm.x += b.x;   sm.y += b.y;
          sf2.x += a2.x; sf2.y += a2.y; sm2.x += b2.x; sm2.y += b2.y;
        }
        rzF[4 + p] = sf; rzM[4 + p] = sm;
        rzF2[4 + p] = sf2; rzM2[4 + p] = sm2;
      }

      if (t >= z0 + 2) {
#pragma unroll
        for (int q = 0; q < 2; ++q) {
          const int zo = t - 2 + q;
          float2 bF = {0.f, 0.f}, bM = {0.f, 0.f};
          float2 bF2 = {0.f, 0.f}, bM2 = {0.f, 0.f};
#pragma unroll
          for (int s = 0; s < 5; ++s) {
            bF.x += rzF[q + s].x;   bF.y += rzF[q + s].y;
            bM.x += rzM[q + s].x;   bM.y += rzM[q + s].y;
            bF2.x += rzF2[q + s].x; bF2.y += rzF2[q + s].y;
            bM2.x += rzM2[q + s].x; bM2.y += rzM2[q + s].y;
          }
          float2 o;
          {
            const float uF = bF.x * INV_SZ, uM = bM.x * INV_SZ;
            const float vF = fmaxf(bF2.x * INV_SZ - uF * uF, 0.f);
            const float vM = fmaxf(bM2.x * INV_SZ - uM * uM, 0.f);
            o.x = ((cnF[q].x - uF) * (cnM[q].x - uM)) /
                  ((sqrtf(vF) + EPS_) * (sqrtf(vM) + EPS_));
          }
          {
            const float uF = bF.y * INV_SZ, uM = bM.y * INV_SZ;
            const float vF = fmaxf(bF2.y * INV_SZ - uF * uF, 0.f);
            const float vM = fmaxf(bM2.y * INV_SZ - uM * uM, 0.f);
            o.y = ((cnF[q].y - uF) * (cnM[q].y - uM)) /
                  ((sqrtf(vF) + EPS_) * (sqrtf(vM) + EPS_));
          }
          *(float2*)&outP[base + (size_t)zo * PLANE + sOff] = o;
        }
      }
    }
  };

  // prologue: raw[0] <- pair(z0-2); s1 <- pair(z0)
  loadPair(z0 - 2, s0A, s0B);
  depositPair(0, s0A, s0B);
  loadPair(z0, s1A, s1B);
  __syncthreads();

  // 18 pair-iters (FZC=32), unrolled x2 for compile-time buf
  for (int t = z0 - 2; t <= z0 + FZC; t += 4) {
    body(0, t,     s1A, s1B, s0A, s0B);
    body(1, t + 2, s0A, s0B, s1A, s1B);
  }
}

// ---------------------------------------------------------------------------
// R10 slab1: cross = box3(p); acc += cross^2 * mask; single barrier per
// pair-iter via the same dbuf + delayed-deposit schedule.
// ---------------------------------------------------------------------------
__global__ __launch_bounds__(BLK) void slab1_reduce(const float* __restrict__ p,
                                                    const float* __restrict__ mask,
                                                    float* __restrict__ out) {
  __shared__ __align__(16) float raw[2][2][SRY][SRX];  // [buf][plane] 20.7KB
  __shared__ __align__(16) float xs [2][2][SRY][SRX];  // 20.7KB
  __shared__ float wsum[BLK / 64];
  constexpr int RAWB = 2 * SRY * SRX;   // floats per buf (2592)

  const int tid = threadIdx.x;
  const int g = blockIdx.x + SNBX * (blockIdx.y + SNBY * blockIdx.z);
  const int w = swz(g);
  const int batch = w / 250, rem = w % 250;
  const int zc = rem / SNXY, tl = rem % SNXY;
  const int x0 = (tl % SNBX) * STX;
  const int y0 = (tl / SNBX) * STY;
  const int z0 = zc * SZC;
  const size_t base = (size_t)batch * VOL;

  int off[3]; float* ld0[3][2];
  bool act[3];
#pragma unroll
  for (int j = 0; j < 3; ++j) {
    int i = tid + j * BLK;
    act[j] = i < SNRAW;
    int ii = act[j] ? i : 0;
    const int ry = ii / SRX, rx = ii % SRX;
    off[j] = clampi(y0 - 2 + ry) * LEN + clampi(x0 - 2 + rx);
#pragma unroll
    for (int pp = 0; pp < 2; ++pp) ld0[j][pp] = &raw[0][pp][ry][rx];
  }
  const int ly  = tid >> 4;
  const int lx0 = (tid & 15) * 2;

  float s0[2][3], s1[2][3];
  float2 rz[6];
  float acc = 0.f;

  auto loadPair = [&](int t, float (&r)[2][3]) {
#pragma unroll
    for (int pp = 0; pp < 2; ++pp) {
      const size_t pb = base + (size_t)clampi(t + pp) * PLANE;
#pragma unroll
      for (int j = 0; j < 3; ++j)
        if (act[j]) r[pp][j] = p[pb + off[j]];
    }
  };
  auto depositPair = [&](int buf, float (&r)[2][3]) {
#pragma unroll
    for (int pp = 0; pp < 2; ++pp)
#pragma unroll
      for (int j = 0; j < 3; ++j)
        if (act[j]) ld0[j][pp][buf * RAWB] = r[pp][j];
  };

  auto body = [&](int buf, int t, float (&dep)[2][3], float (&ld)[2][3]) {
    if (t + 2 <= z0 + SZC) depositPair(buf ^ 1, dep);
    if (t + 4 <= z0 + SZC) loadPair(t + 4, ld);

    if (tid < 288) {
      const int c = tid & 7, r = tid >> 3;
#pragma unroll
      for (int pp = 0; pp < 2; ++pp) {
        const float* rp = &raw[buf][pp][r][4 * c];
        const float4 u = *(const float4*)rp;
        const float4 v = *(const float4*)(rp + 4);
        const float m = u.y + u.z + u.w;
        float4 s;
        s.x = m + u.x + v.x;
        s.y = m + v.x + v.y;
        s.z = s.y - u.y + v.z;
        s.w = s.z - u.z + v.w;
        *(float4*)&xs[buf][pp][r][4 * c] = s;
      }
    }

    __syncthreads();   // the ONLY barrier this iteration

#pragma unroll
    for (int s = 0; s < 4; ++s) rz[s] = rz[s + 2];
#pragma unroll
    for (int pp = 0; pp < 2; ++pp) {
      float2 s2 = {0.f, 0.f};
#pragma unroll
      for (int k = 0; k < 5; ++k) {
        const float2 a = *(const float2*)&xs[buf][pp][ly + k][lx0];
        s2.x += a.x; s2.y += a.y;
      }
      rz[4 + pp] = s2;
    }

    if (t >= z0 + 2) {
#pragma unroll
      for (int q = 0; q < 2; ++q) {
        const int zo = t - 2 + q;
        float2 bs = {0.f, 0.f};
#pragma unroll
        for (int s = 0; s < 5; ++s) { bs.x += rz[q + s].x; bs.y += rz[q + s].y; }
        const size_t gg = base + (size_t)zo * PLANE +
                          (size_t)(y0 + ly) * LEN + (x0 + lx0);
        const float2 mk = *(const float2*)&mask[gg];
        acc += bs.x * bs.x * mk.x + bs.y * bs.y * mk.y;
      }
    }
  };

  loadPair(z0 - 2, s0);
  depositPair(0, s0);
  loadPair(z0, s1);
  __syncthreads();

  for (int t = z0 - 2; t <= z0 + SZC; t += 4) {
    body(0, t,     s1, s0);
    body(1, t + 2, s0, s1);
  }

#pragma unroll
  for (int o = 32; o > 0; o >>= 1) acc += __shfl_down(acc, o, 64);
  const int lane = tid & 63, wid = tid >> 6;
  if (lane == 0) wsum[wid] = acc;
  __syncthreads();
  if (tid == 0) {
    float tt = 0.f;
#pragma unroll
    for (int ww = 0; ww < BLK / 64; ++ww) tt += wsum[ww];
    atomicAdd(out, -tt);
  }
}

}  // namespace

extern "C" void kernel_launch(void* const* d_in, const int* in_sizes, int n_in,
                              void* d_out, int out_size, void* d_ws, size_t ws_size,
                              hipStream_t stream) {
  const float* F    = (const float*)d_in[0];
  const float* M    = (const float*)d_in[1];
  const float* mask = (const float*)d_in[2];
  float* out = (float*)d_out;

  float* pB = (float*)d_ws;   // 2*VOL floats = 32.8 MB

  hipMemsetAsync(d_out, 0, sizeof(float), stream);

  dim3 gf(FNBX, FNBY, FNCHZ * 2), blk(BLK);   // 500
  dim3 gs(SNBX, SNBY, SNCHZ * 2);             // 500

  fuseAB<<<gf, blk, 0, stream>>>(F, M, pB);
  slab1_reduce<<<gs, blk, 0, stream>>>(pB, mask, out);
}

// Round 11
// 158.912 us; speedup vs baseline: 2.1560x; 1.0248x over previous
//
#include <hip/hip_runtime.h>

namespace {

constexpr int LEN   = 160;
constexpr int PLANE = LEN * LEN;            // 25600
constexpr int VOL   = LEN * PLANE;          // 4,096,000 per batch
constexpr float INV_SZ = 1.0f / 125.0f;
constexpr float EPS_   = 1e-10f;

constexpr int BLK = 512;

// fuseAB geometry: 32x16 tile, ZC=32 -> 500 blocks
constexpr int FTX = 32, FTY = 16, FZC = 32;
constexpr int FRX = FTX + 4, FRY = FTY + 4;   // 36, 20
constexpr int FNRAW = FRX * FRY;              // 720
constexpr int FNBX = 5, FNBY = 10, FNXY = 50, FNCHZ = 5;
constexpr int PR   = FRY * FRX;               // raw plane stride (720)
constexpr int RAWB = 2 * 2 * PR;              // raw buf stride (2880)
constexpr int PSX  = FRY * FTX;               // xs plane stride (640)
constexpr int AS   = 2 * PSX;                 // xs array stride (1280)
constexpr int XSB  = 4 * 2 * PSX;             // xs buf stride (5120)

// slab1 geometry: 32x32 tile, ZC=16 -> 500 blocks (R10-proven, unchanged)
constexpr int STX = 32, STY = 32, SZC = 16;
constexpr int SRX = STX + 4, SRY = STY + 4;   // 36, 36
constexpr int SNRAW = SRX * SRY;              // 1296
constexpr int SNBX = 5, SNBY = 5, SNXY = 25, SNCHZ = 10;

constexpr int QW = 62, RW = 4;                // m204 bijective XCD swizzle (500)

__device__ __forceinline__ int clampi(int v) {
  return v < 0 ? 0 : (v > LEN - 1 ? LEN - 1 : v);
}

__device__ __forceinline__ int swz(int g) {
  const int xcd = g & 7, idx = g >> 3;
  return (xcd < RW) ? xcd * (QW + 1) + idx
                    : RW * (QW + 1) + (xcd - RW) * QW + idx;
}

// ---------------------------------------------------------------------------
// R11 fuseAB: producer/consumer wave specialization on the R10 single-barrier
// dbuf schedule. Waves 4-7 (producers): ALL global prefetch, deposits, and
// 640 x-sum tasks. Waves 0-3 (consumers): cen + y-sums + emit ONLY.
// Rationale: R8/R9 (+23/+15%) both shortened the y/emit per-wave chain; R10
// barrier-halving was null -> critical path = consumer-wave serial chain,
// which previously also carried staging + double x-tasks. Producers run
// ahead through the barrier while consumers finish y/emit (overlap).
// Handoff audit (1 barrier/iter): deposit raw[b^1]@i -> xsum reads@i+1 (X);
// xsum xs[b]@i -> y reads@i post-bar (X); cen raw[b]@i pre-bar vs deposit
// raw[b]@i+1 pre-bar separated by barrier i (X).
// ---------------------------------------------------------------------------
__global__ __launch_bounds__(BLK) void fuseAB(const float* __restrict__ inA,
                                              const float* __restrict__ inB,
                                              float* __restrict__ outP) {
  __shared__ __align__(16) float raw[2][2][2][FRY][FRX];  // [buf][field][plane] 23KB
  __shared__ __align__(16) float xs [2][4][2][FRY][FTX];  // [buf][arr][plane] 41KB

  const int tid = threadIdx.x;
  const int g = blockIdx.x + FNBX * (blockIdx.y + FNBY * blockIdx.z);
  const int w = swz(g);
  const int batch = w / 250, rem = w % 250;
  const int zc = rem / FNXY, tl = rem % FNXY;
  const int x0 = (tl % FNBX) * FTX;
  const int y0 = (tl / FNBX) * FTY;
  const int z0 = zc * FZC;
  const size_t base = (size_t)batch * VOL;

  const bool prod = tid >= 256;   // waves 4-7
  const int  pt   = tid & 255;

  // ---- producer descriptors (3 rounds of 256) ----
  int off[3]; bool ract[3]; float* rld[3];
#pragma unroll
  for (int k = 0; k < 3; ++k) {
    const int i = pt + k * 256;
    ract[k] = i < FNRAW;
    const int ii = ract[k] ? i : 0;
    const int ry = ii / FRX, rx = ii % FRX;
    off[k] = clampi(y0 - 2 + ry) * LEN + clampi(x0 - 2 + rx);
    rld[k] = &raw[0][0][0][ry][rx];
  }
  // x-task descriptors: tt = p*320 + f*160 + r*8 + c, tt in [0,640)
  const float* txs[3]; float* txd[3]; bool tact2;
#pragma unroll
  for (int k = 0; k < 3; ++k) {
    int tt = pt + k * 256;
    if (tt >= 640) tt = 0;
    const int p = tt / 320, r1 = tt % 320;
    const int f = r1 / 160, r2 = r1 % 160;
    const int r = r2 / 8,  c = r2 % 8;
    txs[k] = &raw[0][f][p][r][4 * c];
    txd[k] = &xs[0][f][p][r][4 * c];
  }
  tact2 = (pt + 512) < 640;   // third x-task only for pt < 128

  // ---- consumer descriptors: 2 adjacent px ----
  const int ly  = pt >> 4;            // 0..15
  const int lx0 = (pt & 15) * 2;
  const int sOff = (y0 + ly) * LEN + (x0 + lx0);
  const float* yb0 = &xs[0][0][0][ly][lx0];

  float sA0[3][2], sB0[3][2], sA1[3][2], sB1[3][2];  // ping-pong prefetch
  float2 rzF[6], rzM[6], rzF2[6], rzM2[6];           // z-rings
  float2 cnF[4], cnM[4];                             // center ring (lag 2)

  auto loadPair = [&](int t, float (&a)[3][2], float (&b)[3][2]) {
#pragma unroll
    for (int p = 0; p < 2; ++p) {
      const size_t pb = base + (size_t)clampi(t + p) * PLANE;
#pragma unroll
      for (int k = 0; k < 3; ++k)
        if (ract[k]) { a[k][p] = inA[pb + off[k]]; b[k][p] = inB[pb + off[k]]; }
    }
  };
  auto depositPair = [&](int buf, float (&a)[3][2], float (&b)[3][2]) {
#pragma unroll
    for (int k = 0; k < 3; ++k)
      if (ract[k]) {
#pragma unroll
        for (int p = 0; p < 2; ++p) {
          rld[k][buf * RAWB + p * PR]          = a[k][p];   // field F
          rld[k][buf * RAWB + 2 * PR + p * PR] = b[k][p];   // field M
        }
      }
  };
  auto xsumTask = [&](int buf, int k) {
    const float* src = txs[k] + buf * RAWB;
    float* dst = txd[k] + buf * XSB;
    const float4 u = *(const float4*)src;
    const float4 v = *(const float4*)(src + 4);
    const float m = u.y + u.z + u.w;
    float4 s;
    s.x = m + u.x + v.x;
    s.y = m + v.x + v.y;
    s.z = s.y - u.y + v.z;
    s.w = s.z - u.z + v.w;
    *(float4*)dst = s;
    float4 uq, vq;
    uq.x = u.x * u.x; uq.y = u.y * u.y; uq.z = u.z * u.z; uq.w = u.w * u.w;
    vq.x = v.x * v.x; vq.y = v.y * v.y; vq.z = v.z * v.z; vq.w = v.w * v.w;
    const float mq = uq.y + uq.z + uq.w;
    float4 q;
    q.x = mq + uq.x + vq.x;
    q.y = mq + vq.x + vq.y;
    q.z = q.y - uq.y + vq.z;
    q.w = q.z - uq.z + vq.w;
    *(float4*)(dst + 2 * AS) = q;
  };

  auto body = [&](int buf, int t,
                  float (&dA)[3][2], float (&dB)[3][2],
                  float (&lA)[3][2], float (&lB)[3][2]) {
    if (prod) {
      if (t + 2 <= z0 + FZC) depositPair(buf ^ 1, dA, dB);   // pair(t+2)
      if (t + 4 <= z0 + FZC) loadPair(t + 4, lA, lB);        // fire & forget
      xsumTask(buf, 0);
      xsumTask(buf, 1);
      if (tact2) xsumTask(buf, 2);
    } else {
      // center ring: shift 2, push cen(t), cen(t+1)
      cnF[0] = cnF[2]; cnF[1] = cnF[3]; cnM[0] = cnM[2]; cnM[1] = cnM[3];
      cnF[2] = *(const float2*)&raw[buf][0][0][ly + 2][lx0 + 2];
      cnF[3] = *(const float2*)&raw[buf][0][1][ly + 2][lx0 + 2];
      cnM[2] = *(const float2*)&raw[buf][1][0][ly + 2][lx0 + 2];
      cnM[3] = *(const float2*)&raw[buf][1][1][ly + 2][lx0 + 2];
    }

    __syncthreads();   // the ONLY barrier this iteration

    if (!prod) {
#pragma unroll
      for (int s = 0; s < 4; ++s) {
        rzF[s] = rzF[s + 2]; rzM[s] = rzM[s + 2];
        rzF2[s] = rzF2[s + 2]; rzM2[s] = rzM2[s + 2];
      }
      const float* yb = yb0 + buf * XSB;
#pragma unroll
      for (int p = 0; p < 2; ++p) {
        float2 sf = {0.f, 0.f}, sm = {0.f, 0.f};
        float2 sf2 = {0.f, 0.f}, sm2 = {0.f, 0.f};
#pragma unroll
        for (int k = 0; k < 5; ++k) {
          const float2 a  = *(const float2*)(yb + 0 * AS + p * PSX + k * FTX);
          const float2 b  = *(const float2*)(yb + 1 * AS + p * PSX + k * FTX);
          const float2 a2 = *(const float2*)(yb + 2 * AS + p * PSX + k * FTX);
          const float2 b2 = *(const float2*)(yb + 3 * AS + p * PSX + k * FTX);
          sf.x += a.x;   sf.y += a.y;   sm.x += b.x;   sm.y += b.y;
          sf2.x += a2.x; sf2.y += a2.y; sm2.x += b2.x; sm2.y += b2.y;
        }
        rzF[4 + p] = sf; rzM[4 + p] = sm;
        rzF2[4 + p] = sf2; rzM2[4 + p] = sm2;
      }

      if (t >= z0 + 2) {
#pragma unroll
        for (int q = 0; q < 2; ++q) {
          const int zo = t - 2 + q;
          float2 bF = {0.f, 0.f}, bM = {0.f, 0.f};
          float2 bF2 = {0.f, 0.f}, bM2 = {0.f, 0.f};
#pragma unroll
          for (int s = 0; s < 5; ++s) {
            bF.x += rzF[q + s].x;   bF.y += rzF[q + s].y;
            bM.x += rzM[q + s].x;   bM.y += rzM[q + s].y;
            bF2.x += rzF2[q + s].x; bF2.y += rzF2[q + s].y;
            bM2.x += rzM2[q + s].x; bM2.y += rzM2[q + s].y;
          }
          float2 o;
          {
            const float uF = bF.x * INV_SZ, uM = bM.x * INV_SZ;
            const float vF = fmaxf(bF2.x * INV_SZ - uF * uF, 0.f);
            const float vM = fmaxf(bM2.x * INV_SZ - uM * uM, 0.f);
            o.x = ((cnF[q].x - uF) * (cnM[q].x - uM)) /
                  ((sqrtf(vF) + EPS_) * (sqrtf(vM) + EPS_));
          }
          {
            const float uF = bF.y * INV_SZ, uM = bM.y * INV_SZ;
            const float vF = fmaxf(bF2.y * INV_SZ - uF * uF, 0.f);
            const float vM = fmaxf(bM2.y * INV_SZ - uM * uM, 0.f);
            o.y = ((cnF[q].y - uF) * (cnM[q].y - uM)) /
                  ((sqrtf(vF) + EPS_) * (sqrtf(vM) + EPS_));
          }
          *(float2*)&outP[base + (size_t)zo * PLANE + sOff] = o;
        }
      }
    }
  };

  // prologue: producers fill raw[0] with pair(z0-2), prefetch pair(z0)
  if (prod) {
    loadPair(z0 - 2, sA0, sB0);
    depositPair(0, sA0, sB0);
    loadPair(z0, sA1, sB1);
  }
  __syncthreads();

  // 18 pair-iters, unrolled x2 for compile-time buf
  for (int t = z0 - 2; t <= z0 + FZC; t += 4) {
    body(0, t,     sA1, sB1, sA0, sB0);
    body(1, t + 2, sA0, sB0, sA1, sB1);
  }
}

// ---------------------------------------------------------------------------
// R10 slab1 (unchanged, proven): cross = box3(p); acc += cross^2 * mask;
// single barrier per pair-iter via dbuf + delayed deposit.
// ---------------------------------------------------------------------------
__global__ __launch_bounds__(BLK) void slab1_reduce(const float* __restrict__ p,
                                                    const float* __restrict__ mask,
                                                    float* __restrict__ out) {
  __shared__ __align__(16) float raw[2][2][SRY][SRX];  // [buf][plane] 20.7KB
  __shared__ __align__(16) float xs [2][2][SRY][SRX];  // 20.7KB
  __shared__ float wsum[BLK / 64];
  constexpr int RAWB1 = 2 * SRY * SRX;   // floats per buf (2592)

  const int tid = threadIdx.x;
  const int g = blockIdx.x + SNBX * (blockIdx.y + SNBY * blockIdx.z);
  const int w = swz(g);
  const int batch = w / 250, rem = w % 250;
  const int zc = rem / SNXY, tl = rem % SNXY;
  const int x0 = (tl % SNBX) * STX;
  const int y0 = (tl / SNBX) * STY;
  const int z0 = zc * SZC;
  const size_t base = (size_t)batch * VOL;

  int off[3]; float* ld0[3][2];
  bool act[3];
#pragma unroll
  for (int j = 0; j < 3; ++j) {
    int i = tid + j * BLK;
    act[j] = i < SNRAW;
    int ii = act[j] ? i : 0;
    const int ry = ii / SRX, rx = ii % SRX;
    off[j] = clampi(y0 - 2 + ry) * LEN + clampi(x0 - 2 + rx);
#pragma unroll
    for (int pp = 0; pp < 2; ++pp) ld0[j][pp] = &raw[0][pp][ry][rx];
  }
  const int ly  = tid >> 4;
  const int lx0 = (tid & 15) * 2;

  float s0[2][3], s1[2][3];
  float2 rz[6];
  float acc = 0.f;

  auto loadPair = [&](int t, float (&r)[2][3]) {
#pragma unroll
    for (int pp = 0; pp < 2; ++pp) {
      const size_t pb = base + (size_t)clampi(t + pp) * PLANE;
#pragma unroll
      for (int j = 0; j < 3; ++j)
        if (act[j]) r[pp][j] = p[pb + off[j]];
    }
  };
  auto depositPair = [&](int buf, float (&r)[2][3]) {
#pragma unroll
    for (int pp = 0; pp < 2; ++pp)
#pragma unroll
      for (int j = 0; j < 3; ++j)
        if (act[j]) ld0[j][pp][buf * RAWB1] = r[pp][j];
  };

  auto body = [&](int buf, int t, float (&dep)[2][3], float (&ld)[2][3]) {
    if (t + 2 <= z0 + SZC) depositPair(buf ^ 1, dep);
    if (t + 4 <= z0 + SZC) loadPair(t + 4, ld);

    if (tid < 288) {
      const int c = tid & 7, r = tid >> 3;
#pragma unroll
      for (int pp = 0; pp < 2; ++pp) {
        const float* rp = &raw[buf][pp][r][4 * c];
        const float4 u = *(const float4*)rp;
        const float4 v = *(const float4*)(rp + 4);
        const float m = u.y + u.z + u.w;
        float4 s;
        s.x = m + u.x + v.x;
        s.y = m + v.x + v.y;
        s.z = s.y - u.y + v.z;
        s.w = s.z - u.z + v.w;
        *(float4*)&xs[buf][pp][r][4 * c] = s;
      }
    }

    __syncthreads();   // the ONLY barrier this iteration

#pragma unroll
    for (int s = 0; s < 4; ++s) rz[s] = rz[s + 2];
#pragma unroll
    for (int pp = 0; pp < 2; ++pp) {
      float2 s2 = {0.f, 0.f};
#pragma unroll
      for (int k = 0; k < 5; ++k) {
        const float2 a = *(const float2*)&xs[buf][pp][ly + k][lx0];
        s2.x += a.x; s2.y += a.y;
      }
      rz[4 + pp] = s2;
    }

    if (t >= z0 + 2) {
#pragma unroll
      for (int q = 0; q < 2; ++q) {
        const int zo = t - 2 + q;
        float2 bs = {0.f, 0.f};
#pragma unroll
        for (int s = 0; s < 5; ++s) { bs.x += rz[q + s].x; bs.y += rz[q + s].y; }
        const size_t gg = base + (size_t)zo * PLANE +
                          (size_t)(y0 + ly) * LEN + (x0 + lx0);
        const float2 mk = *(const float2*)&mask[gg];
        acc += bs.x * bs.x * mk.x + bs.y * bs.y * mk.y;
      }
    }
  };

  loadPair(z0 - 2, s0);
  depositPair(0, s0);
  loadPair(z0, s1);
  __syncthreads();

  for (int t = z0 - 2; t <= z0 + SZC; t += 4) {
    body(0, t,     s1, s0);
    body(1, t + 2, s0, s1);
  }

#pragma unroll
  for (int o = 32; o > 0; o >>= 1) acc += __shfl_down(acc, o, 64);
  const int lane = tid & 63, wid = tid >> 6;
  if (lane == 0) wsum[wid] = acc;
  __syncthreads();
  if (tid == 0) {
    float tt = 0.f;
#pragma unroll
    for (int ww = 0; ww < BLK / 64; ++ww) tt += wsum[ww];
    atomicAdd(out, -tt);
  }
}

}  // namespace

extern "C" void kernel_launch(void* const* d_in, const int* in_sizes, int n_in,
                              void* d_out, int out_size, void* d_ws, size_t ws_size,
                              hipStream_t stream) {
  const float* F    = (const float*)d_in[0];
  const float* M    = (const float*)d_in[1];
  const float* mask = (const float*)d_in[2];
  float* out = (float*)d_out;

  float* pB = (float*)d_ws;   // 2*VOL floats = 32.8 MB

  hipMemsetAsync(d_out, 0, sizeof(float), stream);

  dim3 gf(FNBX, FNBY, FNCHZ * 2), blk(BLK);   // 500
  dim3 gs(SNBX, SNBY, SNCHZ * 2);             // 500

  fuseAB<<<gf, blk, 0, stream>>>(F, M, pB);
  slab1_reduce<<<gs, blk, 0, stream>>>(pB, mask, out);
}